// Round 4
// baseline (287.256 us; speedup 1.0000x reference)
//
#include <hip/hip_runtime.h>

#define NN 4096      // nodes
#define IND 512      // input dim
#define HD 512       // H*D
#define NH 4         // heads
#define DH 128       // per-head dim
#define K3 1536      // split-K for support GEMM

typedef __attribute__((ext_vector_type(8))) short bf16x8;
typedef __attribute__((ext_vector_type(4))) float f32x4;
typedef __attribute__((ext_vector_type(4))) unsigned short us4;
typedef __attribute__((ext_vector_type(8))) unsigned short us8;

typedef __attribute__((address_space(3))) void lds_void;
typedef const __attribute__((address_space(1))) void glob_void;

__device__ __forceinline__ void gll16(const void* g, void* l) {
  __builtin_amdgcn_global_load_lds((glob_void*)g, (lds_void*)l, 16, 0, 0);
}

__device__ __forceinline__ unsigned short f2bf(float x) {
  union { float f; unsigned u; } a; a.f = x;
  unsigned r = a.u + 0x7FFFu + ((a.u >> 16) & 1u);
  return (unsigned short)(r >> 16);
}
__device__ __forceinline__ float bf2f(unsigned short b) {
  union { float f; unsigned u; } a; a.u = ((unsigned)b) << 16;
  return a.f;
}

// ---------------- prep: inputs -> A3 = [Ah | Ah | Al] (bf16, [4096][1536]) ----
__global__ __launch_bounds__(256) void prep_inputs(const float* __restrict__ x,
                                                   unsigned short* __restrict__ A3) {
  int idx = blockIdx.x * 256 + threadIdx.x;
  int n = idx >> 9, c = idx & 511;
  float v = x[idx];
  unsigned short hi = f2bf(v);
  unsigned short lo = f2bf(v - bf2f(hi));
  size_t base = (size_t)n * K3;
  A3[base + c] = hi;
  A3[base + 512 + c] = hi;
  A3[base + 1024 + c] = lo;
}

// ---------------- prep: weights -> B3T [512 c][1536 k] = [Wh;Wl;Wh]^T, PhT ----
__global__ __launch_bounds__(256) void prep_weights(const float* __restrict__ w,
                                                    const float* __restrict__ pw,
                                                    unsigned short* __restrict__ B3T,
                                                    unsigned short* __restrict__ PhT) {
  int idx = blockIdx.x * 256 + threadIdx.x;
  int c = idx >> 9, k = idx & 511;
  float v = w[(size_t)k * HD + c];
  unsigned short hi = f2bf(v);
  unsigned short lo = f2bf(v - bf2f(hi));
  size_t base = (size_t)c * K3;
  B3T[base + k] = hi;
  B3T[base + 512 + k] = lo;
  B3T[base + 1024 + k] = hi;
  float p = pw[(size_t)k * HD + c];
  PhT[(size_t)c * IND + k] = f2bf(p);
}

// ---------------- GEMM: 128x64 tiles, gll-staged dbuf, XOR-swizzled LDS ------
// z=0: support = A3 @ B3T^T (K=1536 split-bf16), writes support f32 + ST bf16^T
// z=1: resid   = Ah @ PhT^T (K=512) + projb + bias
__global__ __launch_bounds__(256) void gemm_kernel(
    const unsigned short* __restrict__ A3, const unsigned short* __restrict__ B3T,
    const unsigned short* __restrict__ PhT,
    float* __restrict__ support, unsigned short* __restrict__ ST,
    float* __restrict__ resid,
    const float* __restrict__ projb, const float* __restrict__ bias) {
  const int z = blockIdx.z;
  const unsigned short* Bp = z ? PhT : B3T;
  const int ldb = z ? IND : K3;
  const int K = z ? IND : K3;
  const int m0 = blockIdx.x * 128;
  const int n0 = blockIdx.y * 64;
  const int tid = threadIdx.x;
  const int lane = tid & 63;
  const int wv = tid >> 6;
  const int wm = wv & 1, wn = wv >> 1;

  __shared__ unsigned short As[2][128 * 32];
  __shared__ unsigned short Bs[2][64 * 32];

  f32x4 acc[4][2];
#pragma unroll
  for (int a = 0; a < 4; ++a)
#pragma unroll
    for (int b = 0; b < 2; ++b) acc[a][b] = (f32x4){0.f, 0.f, 0.f, 0.f};

  // LDS slot sl of row rr holds global k-chunk ko = sl ^ ((rr>>1)&3)  (rule 21:
  // linear gll16 dest + pre-swizzled global source; read applies the same XOR)
  auto STAGE = [&](int buf, int k0) {
#pragma unroll
    for (int s = 0; s < 2; ++s) {
      int c = s * 256 + tid;
      int rr = c >> 2, sl = c & 3;
      int ko = sl ^ ((rr >> 1) & 3);
      gll16(A3 + (size_t)(m0 + rr) * K3 + k0 + ko * 8, &As[buf][c * 8]);
    }
    {
      int c = tid;
      int rr = c >> 2, sl = c & 3;
      int ko = sl ^ ((rr >> 1) & 3);
      gll16(Bp + (size_t)(n0 + rr) * ldb + k0 + ko * 8, &Bs[buf][c * 8]);
    }
  };

  STAGE(0, 0);
  __syncthreads();

  const int lrow = lane & 15;
  const int kgc = lane >> 4;                 // k-chunk wanted
  int buf = 0;
  for (int k0 = 0; k0 < K; k0 += 32) {
    if (k0 + 32 < K) STAGE(buf ^ 1, k0 + 32);
    bf16x8 af[4], bfr[2];
#pragma unroll
    for (int mf = 0; mf < 4; ++mf) {
      int arow = wm * 64 + mf * 16 + lrow;
      int asl = kgc ^ ((arow >> 1) & 3);
      af[mf] = *(const bf16x8*)(&As[buf][arow * 32 + asl * 8]);
    }
#pragma unroll
    for (int nf = 0; nf < 2; ++nf) {
      int brow = wn * 32 + nf * 16 + lrow;
      int bsl = kgc ^ ((brow >> 1) & 3);
      bfr[nf] = *(const bf16x8*)(&Bs[buf][brow * 32 + bsl * 8]);
    }
#pragma unroll
    for (int mf = 0; mf < 4; ++mf)
#pragma unroll
      for (int nf = 0; nf < 2; ++nf)
        acc[mf][nf] = __builtin_amdgcn_mfma_f32_16x16x32_bf16(af[mf], bfr[nf], acc[mf][nf], 0, 0, 0);
    __syncthreads();
    buf ^= 1;
  }

  const int lrow4 = (lane >> 4) * 4;
  const int lcol = lane & 15;
  if (z == 0) {
#pragma unroll
    for (int mf = 0; mf < 4; ++mf) {
#pragma unroll
      for (int nf = 0; nf < 2; ++nf) {
        int rg = m0 + wm * 64 + mf * 16 + lrow4;
        int cg = n0 + wn * 32 + nf * 16 + lcol;
#pragma unroll
        for (int q = 0; q < 4; ++q)
          support[(size_t)(rg + q) * HD + cg] = acc[mf][nf][q];
        us4 st4;
#pragma unroll
        for (int q = 0; q < 4; ++q) st4[q] = f2bf(acc[mf][nf][q]);
        *(us4*)(ST + (size_t)cg * NN + rg) = st4;
      }
    }
  } else {
#pragma unroll
    for (int mf = 0; mf < 4; ++mf) {
#pragma unroll
      for (int nf = 0; nf < 2; ++nf) {
        int rg = m0 + wm * 64 + mf * 16 + lrow4;
        int cg = n0 + wn * 32 + nf * 16 + lcol;
        float addv = projb[cg] + bias[cg];
#pragma unroll
        for (int q = 0; q < 4; ++q)
          resid[(size_t)(rg + q) * HD + cg] = acc[mf][nf][q] + addv;
      }
    }
  }
}

// ---------------- f1/f2 (scaled by log2 e) ----------------------------------
__global__ __launch_bounds__(256) void f1f2_kernel(const float* __restrict__ support,
                                                   const float* __restrict__ wu,
                                                   const float* __restrict__ wv,
                                                   float* __restrict__ g1,
                                                   float* __restrict__ g2) {
  int lane = threadIdx.x & 63;
  int n = blockIdx.x * 4 + (threadIdx.x >> 6);
  const float* srow = support + (size_t)n * HD + lane * 8;
  int h = lane >> 4;
  int d0 = (lane * 8) & 127;
  const float* u = wu + h * DH + d0;
  const float* v = wv + h * DH + d0;
  float du = 0.f, dv = 0.f;
#pragma unroll
  for (int e = 0; e < 8; ++e) {
    float s = srow[e];
    du += s * u[e];
    dv += s * v[e];
  }
#pragma unroll
  for (int off = 1; off < 16; off <<= 1) {
    du += __shfl_xor(du, off);
    dv += __shfl_xor(dv, off);
  }
  if ((lane & 15) == 0) {
    const float L2E = 1.4426950408889634f;
    g1[h * NN + n] = du * L2E;
    g2[h * NN + n] = dv * L2E;
  }
}

// ---------------- adjacency -> bitmask (pure ballot, HBM-bound) --------------
__global__ __launch_bounds__(256) void ballot_kernel(const float* __restrict__ adj,
                                                     unsigned long long* __restrict__ bm) {
  int i = blockIdx.x;
  int tid = threadIdx.x, lane = tid & 63, wv = tid >> 6;
  const float* arow = adj + (size_t)i * NN;
#pragma unroll 4
  for (int it = 0; it < 16; ++it) {
    int j = it * 256 + tid;
    unsigned long long b = __ballot(arow[j] != 0.0f);
    if (lane == 0) bm[(size_t)i * 64 + it * 4 + wv] = b;
  }
}

// ---------------- fused masked softmax + PV (reg-staged ST, no barriers) -----
// grid (64 row-tiles, 4 heads, 2 j-chunks); 4 waves = 4 row-groups of 16.
__global__ __launch_bounds__(256) void attn_kernel(
    const unsigned short* __restrict__ ST,        // [512 d][4096 j] bf16
    const unsigned long long* __restrict__ bm,    // [4096 i][64 words]
    const float* __restrict__ g1, const float* __restrict__ g2,
    float* __restrict__ P, float* __restrict__ S) {
  const int bx = blockIdx.x;
  const int by = blockIdx.y;   // head
  const int bz = blockIdx.z;   // j-chunk (2048)
  const int tid = threadIdx.x;
  const int lane = tid & 63;
  const int w = tid >> 6;      // row-group

  __shared__ unsigned long long bml[32 * 64];     // 16KB transposed: [word][row]
  __shared__ float g1l[2048];                     // 8KB

  {
    const unsigned long long* bsrc = bm + (size_t)bx * 64 * 64 + bz * 32;
#pragma unroll
    for (int s = 0; s < 8; ++s) {
      int idx = s * 256 + tid;               // 0..2047
      int wd = idx & 31, r = idx >> 5;       // coalesced global read
      bml[wd * 64 + r] = bsrc[(size_t)r * 64 + wd];
    }
    const float* gsrc = g1 + by * NN + bz * 2048;
#pragma unroll
    for (int s = 0; s < 2; ++s) {
      int idx = s * 256 + tid;
      *(f32x4*)(g1l + idx * 4) = *(const f32x4*)(gsrc + idx * 4);
    }
  }

  const int il = lane & 15;
  const int kg = lane >> 4;
  const int r = w * 16 + il;                 // local row 0..63
  const int ig = bx * 64 + r;
  const float g2v = g2[by * NN + ig];
  const float g2v5 = 0.2f * g2v;
  const unsigned short* stp = ST + (size_t)(by * 128 + il) * NN + bz * 2048 + kg * 8;

  __syncthreads();

  bf16x8 ones;
#pragma unroll
  for (int e = 0; e < 8; ++e) ones[e] = (short)0x3F80;

  f32x4 acc[8];
#pragma unroll
  for (int d = 0; d < 8; ++d) acc[d] = (f32x4){0.f, 0.f, 0.f, 0.f};
  f32x4 asum = (f32x4){0.f, 0.f, 0.f, 0.f};

  const char* bmlB = (const char*)bml;

  bf16x8 st0[8], st1[8];
#pragma unroll
  for (int d = 0; d < 8; ++d) st0[d] = *(const bf16x8*)(stp + (size_t)d * 16 * NN);

#define COMPUTE(SREG, JT)                                                        \
  {                                                                              \
    int b = ((JT) >> 3) + kg;                                                    \
    unsigned mby = (unsigned char)bmlB[((b >> 3) * 64 + r) * 8 + (b & 7)];       \
    union F8 { f32x4 v[2]; float f[8]; } gc;                                     \
    gc.v[0] = *(const f32x4*)(g1l + (JT) + kg * 8);                              \
    gc.v[1] = *(const f32x4*)(g1l + (JT) + kg * 8 + 4);                          \
    float p[8];                                                                  \
    _Pragma("unroll")                                                            \
    for (int e = 0; e < 8; ++e) {                                                \
      float a = gc.f[e] + g2v;                                                   \
      float bb = __builtin_fmaf(0.2f, gc.f[e], g2v5);                            \
      float m = fmaxf(a, bb);                                                    \
      float pe = __builtin_amdgcn_exp2f(m);                                      \
      int sext = -(int)((mby >> e) & 1u);                                        \
      union { float f; unsigned u; } pu; pu.f = pe;                              \
      pu.u &= (unsigned)sext;                                                    \
      p[e] = pu.f;                                                               \
    }                                                                            \
    union { unsigned u[4]; bf16x8 v; } af;                                       \
    _Pragma("unroll")                                                            \
    for (int e2 = 0; e2 < 4; ++e2) {                                             \
      unsigned pk;                                                               \
      asm("v_cvt_pk_bf16_f32 %0, %1, %2" : "=v"(pk) : "v"(p[2*e2]), "v"(p[2*e2+1])); \
      af.u[e2] = pk;                                                             \
    }                                                                            \
    _Pragma("unroll")                                                            \
    for (int d = 0; d < 8; ++d)                                                  \
      acc[d] = __builtin_amdgcn_mfma_f32_16x16x32_bf16(af.v, SREG[d], acc[d], 0, 0, 0); \
    asum = __builtin_amdgcn_mfma_f32_16x16x32_bf16(af.v, ones, asum, 0, 0, 0);   \
  }

  for (int jt = 0; jt < 2048; jt += 64) {
    {
      int jn = (jt + 32) & 2047;
#pragma unroll
      for (int d = 0; d < 8; ++d) st1[d] = *(const bf16x8*)(stp + (size_t)d * 16 * NN + jn);
      COMPUTE(st0, jt)
    }
    {
      int jn = (jt + 64) & 2047;
#pragma unroll
      for (int d = 0; d < 8; ++d) st0[d] = *(const bf16x8*)(stp + (size_t)d * 16 * NN + jn);
      COMPUTE(st1, jt + 32)
    }
  }
#undef COMPUTE

  // write partials
  float* Pp = P + (size_t)bz * NN * HD;
#pragma unroll
  for (int d = 0; d < 8; ++d) {
    int cg = by * 128 + d * 16 + il;
#pragma unroll
    for (int q = 0; q < 4; ++q) {
      int rg = bx * 64 + w * 16 + kg * 4 + q;
      Pp[(size_t)rg * HD + cg] = acc[d][q];
    }
  }
  if (il == 0) {
#pragma unroll
    for (int q = 0; q < 4; ++q) {
      int rg = bx * 64 + w * 16 + kg * 4 + q;
      S[((size_t)bz * 4 + by) * NN + rg] = asum[q];
    }
  }
}

// ---------------- merge partials + normalize + residual ----------------------
__global__ __launch_bounds__(256) void merge_kernel(const float* __restrict__ P,
                                                    const float* __restrict__ S,
                                                    const float* __restrict__ resid,
                                                    float* __restrict__ out) {
  int idx = blockIdx.x * 256 + threadIdx.x;   // 0..524287 (f32x4 groups)
  int i = idx >> 7;
  int c = (idx & 127) * 4;
  int h = c >> 7;
  f32x4 v0 = *(const f32x4*)(P + (size_t)i * HD + c);
  f32x4 v1 = *(const f32x4*)(P + (size_t)(NN + i) * HD + c);
  float s = S[(size_t)h * NN + i] + S[(size_t)(4 + h) * NN + i];
  float rs = s > 0.0f ? 1.0f / s : 0.0f;
  f32x4 rr = *(const f32x4*)(resid + (size_t)i * HD + c);
  f32x4 o;
#pragma unroll
  for (int q = 0; q < 4; ++q) o[q] = (v0[q] + v1[q]) * rs + rr[q];
  *(f32x4*)(out + (size_t)i * HD + c) = o;
}

// ---------------- launcher ---------------------------------------------------
extern "C" void kernel_launch(void* const* d_in, const int* in_sizes, int n_in,
                              void* d_out, int out_size, void* d_ws, size_t ws_size,
                              hipStream_t stream) {
  const float* inputs = (const float*)d_in[0];
  const float* adj = (const float*)d_in[1];
  const float* weight = (const float*)d_in[2];
  const float* wu = (const float*)d_in[3];
  const float* wv = (const float*)d_in[4];
  const float* bias = (const float*)d_in[5];
  const float* projw = (const float*)d_in[6];
  const float* projb = (const float*)d_in[7];
  float* out = (float*)d_out;

  char* ws = (char*)d_ws;
  size_t off = 0;
  unsigned short* A3 = (unsigned short*)(ws + off); off += (size_t)NN * K3 * 2;          // 12.58MB
  unsigned short* B3T = (unsigned short*)(ws + off); off += (size_t)HD * K3 * 2;         // 1.57MB
  unsigned short* PhT = (unsigned short*)(ws + off); off += (size_t)HD * IND * 2;        // 0.52MB
  float* support = (float*)(ws + off); off += (size_t)NN * HD * 4;                       // 8MB (ends 22.67MB)
  unsigned short* ST = (unsigned short*)(ws + off); off += (size_t)HD * NN * 2;          // 4MB
  float* resid = (float*)(ws + off); off += (size_t)NN * HD * 4;                         // 8MB
  float* g1 = (float*)(ws + off); off += (size_t)NH * NN * 4;
  float* g2 = (float*)(ws + off); off += (size_t)NH * NN * 4;
  unsigned long long* bm = (unsigned long long*)(ws + off); off += (size_t)NN * 64 * 8;  // 2MB

  // P/S OVERLAY dead buffers (A3/B3T/PhT/support are dead by the time attn runs):
  // P = ws+0 .. 16.78MB ; S = ws+17MB .. +128KB  (both < 22.67MB = end of support)
  float* P = (float*)(ws + 0);
  float* S = (float*)(ws + (size_t)17 * 1024 * 1024);

  prep_inputs<<<(NN * IND) / 256, 256, 0, stream>>>(inputs, A3);
  prep_weights<<<(IND * HD) / 256, 256, 0, stream>>>(weight, projw, B3T, PhT);
  gemm_kernel<<<dim3(32, 8, 2), 256, 0, stream>>>(A3, B3T, PhT, support, ST, resid, projb, bias);
  f1f2_kernel<<<NN / 4, 256, 0, stream>>>(support, wu, wv, g1, g2);
  ballot_kernel<<<NN, 256, 0, stream>>>(adj, bm);
  attn_kernel<<<dim3(64, 4, 2), 256, 0, stream>>>(ST, bm, g1, g2, P, S);
  merge_kernel<<<2048, 256, 0, stream>>>(P, S, resid, out);
}

// Round 5
// 208.601 us; speedup vs baseline: 1.3771x; 1.3771x over previous
//
#include <hip/hip_runtime.h>

#define NN 4096      // nodes
#define IND 512      // input dim
#define HD 512       // H*D
#define NH 4         // heads
#define DH 128       // per-head dim
#define K3 1536      // split-K for support GEMM

typedef __attribute__((ext_vector_type(8))) short bf16x8;
typedef __attribute__((ext_vector_type(4))) float f32x4;
typedef __attribute__((ext_vector_type(4))) unsigned short us4;
typedef __attribute__((ext_vector_type(8))) unsigned short us8;

typedef __attribute__((address_space(3))) void lds_void;
typedef const __attribute__((address_space(1))) void glob_void;

__device__ __forceinline__ void gll16(const void* g, void* l) {
  __builtin_amdgcn_global_load_lds((glob_void*)g, (lds_void*)l, 16, 0, 0);
}

__device__ __forceinline__ unsigned short f2bf(float x) {
  union { float f; unsigned u; } a; a.f = x;
  unsigned r = a.u + 0x7FFFu + ((a.u >> 16) & 1u);
  return (unsigned short)(r >> 16);
}
__device__ __forceinline__ float bf2f(unsigned short b) {
  union { float f; unsigned u; } a; a.u = ((unsigned)b) << 16;
  return a.f;
}

// ---------------- prep: inputs -> A3 = [Ah | Ah | Al] (bf16, [4096][1536]) ----
__global__ __launch_bounds__(256) void prep_inputs(const float* __restrict__ x,
                                                   unsigned short* __restrict__ A3) {
  int idx = blockIdx.x * 256 + threadIdx.x;
  int n = idx >> 9, c = idx & 511;
  float v = x[idx];
  unsigned short hi = f2bf(v);
  unsigned short lo = f2bf(v - bf2f(hi));
  size_t base = (size_t)n * K3;
  A3[base + c] = hi;
  A3[base + 512 + c] = hi;
  A3[base + 1024 + c] = lo;
}

// ---------------- prep: weights -> B3T [512 c][1536 k] = [Wh;Wl;Wh]^T, PhT ----
__global__ __launch_bounds__(256) void prep_weights(const float* __restrict__ w,
                                                    const float* __restrict__ pw,
                                                    unsigned short* __restrict__ B3T,
                                                    unsigned short* __restrict__ PhT) {
  int idx = blockIdx.x * 256 + threadIdx.x;
  int c = idx >> 9, k = idx & 511;
  float v = w[(size_t)k * HD + c];
  unsigned short hi = f2bf(v);
  unsigned short lo = f2bf(v - bf2f(hi));
  size_t base = (size_t)c * K3;
  B3T[base + k] = hi;
  B3T[base + 512 + k] = lo;
  B3T[base + 1024 + k] = hi;
  float p = pw[(size_t)k * HD + c];
  PhT[(size_t)c * IND + k] = f2bf(p);
}

// ---------------- GEMM: 128x64 tiles, BK=64 gll dbuf, 8-slot XOR swizzle -----
// z=0: support = A3 @ B3T^T (K=1536 split-bf16), writes support f32 + ST bf16^T
// z=1: resid   = Ah @ PhT^T (K=512) + projb + bias
__global__ __launch_bounds__(256) void gemm_kernel(
    const unsigned short* __restrict__ A3, const unsigned short* __restrict__ B3T,
    const unsigned short* __restrict__ PhT,
    float* __restrict__ support, unsigned short* __restrict__ ST,
    float* __restrict__ resid,
    const float* __restrict__ projb, const float* __restrict__ bias) {
  const int z = blockIdx.z;
  const unsigned short* Bp = z ? PhT : B3T;
  const int ldb = z ? IND : K3;
  const int K = z ? IND : K3;
  const int m0 = blockIdx.x * 128;
  const int n0 = blockIdx.y * 64;
  const int tid = threadIdx.x;
  const int lane = tid & 63;
  const int wv = tid >> 6;
  const int wm = wv & 1, wn = wv >> 1;

  __shared__ unsigned short As[2][128 * 64];   // 32KB: [row][64 k] 128B rows
  __shared__ unsigned short Bs[2][64 * 64];    // 16KB

  f32x4 acc[4][2];
#pragma unroll
  for (int a = 0; a < 4; ++a)
#pragma unroll
    for (int b = 0; b < 2; ++b) acc[a][b] = (f32x4){0.f, 0.f, 0.f, 0.f};

  // slot sl of row rr holds k-chunk sl^(rr&7) (rule 21: linear gll dest,
  // pre-swizzled global source; read applies same XOR -> 2-way, free)
  auto STAGE = [&](int buf, int k0) {
#pragma unroll
    for (int s = 0; s < 4; ++s) {
      int c = s * 256 + tid;
      int rr = c >> 3, sl = c & 7;
      int ko = sl ^ (rr & 7);
      gll16(A3 + (size_t)(m0 + rr) * K3 + k0 + ko * 8, &As[buf][c * 8]);
    }
#pragma unroll
    for (int s = 0; s < 2; ++s) {
      int c = s * 256 + tid;
      int rr = c >> 3, sl = c & 7;
      int ko = sl ^ (rr & 7);
      gll16(Bp + (size_t)(n0 + rr) * ldb + k0 + ko * 8, &Bs[buf][c * 8]);
    }
  };

  STAGE(0, 0);
  __syncthreads();

  const int lrow = lane & 15;
  const int kgc = lane >> 4;                 // k-chunk within 32-k step
  const int sx = lrow & 7;                   // row-XOR (d-independent)
  int buf = 0;
  for (int k0 = 0; k0 < K; k0 += 64) {
    if (k0 + 64 < K) STAGE(buf ^ 1, k0 + 64);
#pragma unroll
    for (int js = 0; js < 64; js += 32) {
      int cb = (js >> 3) + kgc;
      bf16x8 af[4], bfr[2];
#pragma unroll
      for (int mf = 0; mf < 4; ++mf) {
        int row = wm * 64 + mf * 16 + lrow;
        af[mf] = *(const bf16x8*)(&As[buf][row * 64 + (cb ^ sx) * 8]);
      }
#pragma unroll
      for (int nf = 0; nf < 2; ++nf) {
        int row = wn * 32 + nf * 16 + lrow;
        bfr[nf] = *(const bf16x8*)(&Bs[buf][row * 64 + (cb ^ sx) * 8]);
      }
#pragma unroll
      for (int mf = 0; mf < 4; ++mf)
#pragma unroll
        for (int nf = 0; nf < 2; ++nf)
          acc[mf][nf] = __builtin_amdgcn_mfma_f32_16x16x32_bf16(af[mf], bfr[nf], acc[mf][nf], 0, 0, 0);
    }
    __syncthreads();
    buf ^= 1;
  }

  const int lrow4 = (lane >> 4) * 4;
  const int lcol = lane & 15;
  if (z == 0) {
#pragma unroll
    for (int mf = 0; mf < 4; ++mf) {
#pragma unroll
      for (int nf = 0; nf < 2; ++nf) {
        int rg = m0 + wm * 64 + mf * 16 + lrow4;
        int cg = n0 + wn * 32 + nf * 16 + lcol;
#pragma unroll
        for (int q = 0; q < 4; ++q)
          support[(size_t)(rg + q) * HD + cg] = acc[mf][nf][q];
        us4 st4;
#pragma unroll
        for (int q = 0; q < 4; ++q) st4[q] = f2bf(acc[mf][nf][q]);
        *(us4*)(ST + (size_t)cg * NN + rg) = st4;
      }
    }
  } else {
#pragma unroll
    for (int mf = 0; mf < 4; ++mf) {
#pragma unroll
      for (int nf = 0; nf < 2; ++nf) {
        int rg = m0 + wm * 64 + mf * 16 + lrow4;
        int cg = n0 + wn * 32 + nf * 16 + lcol;
        float addv = projb[cg] + bias[cg];
#pragma unroll
        for (int q = 0; q < 4; ++q)
          resid[(size_t)(rg + q) * HD + cg] = acc[mf][nf][q] + addv;
      }
    }
  }
}

// ---------------- f1/f2 (scaled by log2 e) ----------------------------------
__global__ __launch_bounds__(256) void f1f2_kernel(const float* __restrict__ support,
                                                   const float* __restrict__ wu,
                                                   const float* __restrict__ wv,
                                                   float* __restrict__ g1,
                                                   float* __restrict__ g2) {
  int lane = threadIdx.x & 63;
  int n = blockIdx.x * 4 + (threadIdx.x >> 6);
  const float* srow = support + (size_t)n * HD + lane * 8;
  int h = lane >> 4;
  int d0 = (lane * 8) & 127;
  const float* u = wu + h * DH + d0;
  const float* v = wv + h * DH + d0;
  float du = 0.f, dv = 0.f;
#pragma unroll
  for (int e = 0; e < 8; ++e) {
    float s = srow[e];
    du += s * u[e];
    dv += s * v[e];
  }
#pragma unroll
  for (int off = 1; off < 16; off <<= 1) {
    du += __shfl_xor(du, off);
    dv += __shfl_xor(dv, off);
  }
  if ((lane & 15) == 0) {
    const float L2E = 1.4426950408889634f;
    g1[h * NN + n] = du * L2E;
    g2[h * NN + n] = dv * L2E;
  }
}

// ---------------- adjacency -> bitmask (pure ballot, HBM-bound) --------------
__global__ __launch_bounds__(256) void ballot_kernel(const float* __restrict__ adj,
                                                     unsigned long long* __restrict__ bm) {
  int i = blockIdx.x;
  int tid = threadIdx.x, lane = tid & 63, wv = tid >> 6;
  const float* arow = adj + (size_t)i * NN;
#pragma unroll 4
  for (int it = 0; it < 16; ++it) {
    int j = it * 256 + tid;
    unsigned long long b = __ballot(arow[j] != 0.0f);
    if (lane == 0) bm[(size_t)i * 64 + it * 4 + wv] = b;
  }
}

// ---------------- fused masked softmax + PV (swizzled LDS dbuf, j-step 64) ---
// grid (64 row-tiles, 4 heads, 2 j-chunks); 4 waves = 4 row-groups of 16.
__global__ __launch_bounds__(256) void attn_kernel(
    const unsigned short* __restrict__ ST,        // [512 d][4096 j] bf16
    const unsigned long long* __restrict__ bm,    // [4096 i][64 words]
    const float* __restrict__ g1, const float* __restrict__ g2,
    float* __restrict__ P, float* __restrict__ S) {
  const int bx = blockIdx.x;
  const int by = blockIdx.y;   // head
  const int bz = blockIdx.z;   // j-chunk (2048)
  const int tid = threadIdx.x;
  const int lane = tid & 63;
  const int w = tid >> 6;      // row-group

  __shared__ unsigned short tile[2][128 * 64];    // 32KB dbuf: [d-row][64 j] 128B rows
  __shared__ unsigned long long bml[32 * 64];     // 16KB transposed: [word][row]
  __shared__ float g1l[2048];                     // 8KB

  {
    const unsigned long long* bsrc = bm + (size_t)bx * 64 * 64 + bz * 32;
#pragma unroll
    for (int s = 0; s < 8; ++s) {
      int idx = s * 256 + tid;               // 0..2047
      int wd = idx & 31, r = idx >> 5;       // coalesced global read
      bml[wd * 64 + r] = bsrc[(size_t)r * 64 + wd];
    }
    const float* gsrc = g1 + by * NN + bz * 2048;
#pragma unroll
    for (int s = 0; s < 2; ++s) {
      int idx = s * 256 + tid;
      *(f32x4*)(g1l + idx * 4) = *(const f32x4*)(gsrc + idx * 4);
    }
  }

  const int il = lane & 15;
  const int kg = lane >> 4;
  const int r = w * 16 + il;                 // local row 0..63
  const int ig = bx * 64 + r;
  const float g2v = g2[by * NN + ig];
  const float g2v5 = 0.2f * g2v;
  const unsigned short* stbase = ST + (size_t)by * 128 * NN + bz * 2048;

  // slot sl of row rr holds j-chunk sl^(rr&7)
  auto STAGE = [&](int buf, int jt) {
#pragma unroll
    for (int s = 0; s < 4; ++s) {
      int c = s * 256 + tid;                 // 0..1023
      int rr = c >> 3, sl = c & 7;
      int jq = sl ^ (rr & 7);
      gll16(stbase + (size_t)rr * NN + jt + jq * 8, &tile[buf][c * 8]);
    }
  };

  STAGE(0, 0);
  __syncthreads();

  bf16x8 ones;
#pragma unroll
  for (int e = 0; e < 8; ++e) ones[e] = (short)0x3F80;

  f32x4 acc[8];
#pragma unroll
  for (int d = 0; d < 8; ++d) acc[d] = (f32x4){0.f, 0.f, 0.f, 0.f};
  f32x4 asum = (f32x4){0.f, 0.f, 0.f, 0.f};

  const char* bmlB = (const char*)bml;
  const int sx = il & 7;                     // row-XOR (d-independent)
  int buf = 0;

  for (int jt = 0; jt < 2048; jt += 64) {
    if (jt + 64 < 2048) STAGE(buf ^ 1, jt + 64);
#pragma unroll
    for (int js = 0; js < 64; js += 32) {
      int cb = (js >> 3) + kg;
      bf16x8 bc[8];
#pragma unroll
      for (int d = 0; d < 8; ++d)
        bc[d] = *(const bf16x8*)(&tile[buf][(il + d * 16) * 64 + (cb ^ sx) * 8]);

      int jw = jt + js;
      int b = (jw >> 3) + kg;
      unsigned mby = (unsigned char)bmlB[((b >> 3) * 64 + r) * 8 + (b & 7)];
      union F8 { f32x4 v[2]; float f[8]; } gc;
      gc.v[0] = *(const f32x4*)(g1l + jw + kg * 8);
      gc.v[1] = *(const f32x4*)(g1l + jw + kg * 8 + 4);
      float p[8];
#pragma unroll
      for (int e = 0; e < 8; ++e) {
        float a = gc.f[e] + g2v;                        // t*log2e
        float bb = __builtin_fmaf(0.2f, gc.f[e], g2v5); // 0.2*t*log2e
        float m = fmaxf(a, bb);                         // leaky-relu
        float pe = __builtin_amdgcn_exp2f(m);           // no max-sub (shift-invariant)
        int sext = -(int)((mby >> e) & 1u);
        union { float f; unsigned u; } pu; pu.f = pe;
        pu.u &= (unsigned)sext;                         // zero masked-out
        p[e] = pu.f;
      }
      union { unsigned u[4]; bf16x8 v; } af;
#pragma unroll
      for (int e2 = 0; e2 < 4; ++e2) {
        unsigned pk;
        asm("v_cvt_pk_bf16_f32 %0, %1, %2" : "=v"(pk) : "v"(p[2 * e2]), "v"(p[2 * e2 + 1]));
        af.u[e2] = pk;
      }
#pragma unroll
      for (int d = 0; d < 8; ++d)
        acc[d] = __builtin_amdgcn_mfma_f32_16x16x32_bf16(af.v, bc[d], acc[d], 0, 0, 0);
      asum = __builtin_amdgcn_mfma_f32_16x16x32_bf16(af.v, ones, asum, 0, 0, 0);
    }
    __syncthreads();
    buf ^= 1;
  }

  // write partials
  float* Pp = P + (size_t)bz * NN * HD;
#pragma unroll
  for (int d = 0; d < 8; ++d) {
    int cg = by * 128 + d * 16 + il;
#pragma unroll
    for (int q = 0; q < 4; ++q) {
      int rg = bx * 64 + w * 16 + kg * 4 + q;
      Pp[(size_t)rg * HD + cg] = acc[d][q];
    }
  }
  if (il == 0) {
#pragma unroll
    for (int q = 0; q < 4; ++q) {
      int rg = bx * 64 + w * 16 + kg * 4 + q;
      S[((size_t)bz * 4 + by) * NN + rg] = asum[q];
    }
  }
}

// ---------------- merge partials + normalize + residual ----------------------
__global__ __launch_bounds__(256) void merge_kernel(const float* __restrict__ P,
                                                    const float* __restrict__ S,
                                                    const float* __restrict__ resid,
                                                    float* __restrict__ out) {
  int idx = blockIdx.x * 256 + threadIdx.x;   // 0..524287 (f32x4 groups)
  int i = idx >> 7;
  int c = (idx & 127) * 4;
  int h = c >> 7;
  f32x4 v0 = *(const f32x4*)(P + (size_t)i * HD + c);
  f32x4 v1 = *(const f32x4*)(P + (size_t)(NN + i) * HD + c);
  float s = S[(size_t)h * NN + i] + S[(size_t)(4 + h) * NN + i];
  float rs = s > 0.0f ? 1.0f / s : 0.0f;
  f32x4 rr = *(const f32x4*)(resid + (size_t)i * HD + c);
  f32x4 o;
#pragma unroll
  for (int q = 0; q < 4; ++q) o[q] = (v0[q] + v1[q]) * rs + rr[q];
  *(f32x4*)(out + (size_t)i * HD + c) = o;
}

// ---------------- launcher ---------------------------------------------------
extern "C" void kernel_launch(void* const* d_in, const int* in_sizes, int n_in,
                              void* d_out, int out_size, void* d_ws, size_t ws_size,
                              hipStream_t stream) {
  const float* inputs = (const float*)d_in[0];
  const float* adj = (const float*)d_in[1];
  const float* weight = (const float*)d_in[2];
  const float* wu = (const float*)d_in[3];
  const float* wv = (const float*)d_in[4];
  const float* bias = (const float*)d_in[5];
  const float* projw = (const float*)d_in[6];
  const float* projb = (const float*)d_in[7];
  float* out = (float*)d_out;

  char* ws = (char*)d_ws;
  size_t off = 0;
  unsigned short* A3 = (unsigned short*)(ws + off); off += (size_t)NN * K3 * 2;          // 12.58MB
  unsigned short* B3T = (unsigned short*)(ws + off); off += (size_t)HD * K3 * 2;         // 1.57MB
  unsigned short* PhT = (unsigned short*)(ws + off); off += (size_t)HD * IND * 2;        // 0.52MB
  float* support = (float*)(ws + off); off += (size_t)NN * HD * 4;                       // 8MB (ends 22.67MB)
  unsigned short* ST = (unsigned short*)(ws + off); off += (size_t)HD * NN * 2;          // 4MB
  float* resid = (float*)(ws + off); off += (size_t)NN * HD * 4;                         // 8MB
  float* g1 = (float*)(ws + off); off += (size_t)NH * NN * 4;
  float* g2 = (float*)(ws + off); off += (size_t)NH * NN * 4;
  unsigned long long* bm = (unsigned long long*)(ws + off); off += (size_t)NN * 64 * 8;  // 2MB

  // P/S OVERLAY dead buffers (A3/B3T/PhT/support are dead by the time attn runs):
  float* P = (float*)(ws + 0);
  float* S = (float*)(ws + (size_t)17 * 1024 * 1024);

  prep_inputs<<<(NN * IND) / 256, 256, 0, stream>>>(inputs, A3);
  prep_weights<<<(IND * HD) / 256, 256, 0, stream>>>(weight, projw, B3T, PhT);
  gemm_kernel<<<dim3(32, 8, 2), 256, 0, stream>>>(A3, B3T, PhT, support, ST, resid, projb, bias);
  f1f2_kernel<<<NN / 4, 256, 0, stream>>>(support, wu, wv, g1, g2);
  ballot_kernel<<<NN, 256, 0, stream>>>(adj, bm);
  attn_kernel<<<dim3(64, 4, 2), 256, 0, stream>>>(ST, bm, g1, g2, P, S);
  merge_kernel<<<2048, 256, 0, stream>>>(P, S, resid, out);
}

// Round 7
// 200.005 us; speedup vs baseline: 1.4362x; 1.0430x over previous
//
#include <hip/hip_runtime.h>

#define NN 4096      // nodes
#define IND 512      // input dim
#define HD 512       // H*D
#define NH 4         // heads
#define DH 128       // per-head dim
#define K3 1536      // split-K for support GEMM

typedef __attribute__((ext_vector_type(8))) short bf16x8;
typedef __attribute__((ext_vector_type(4))) float f32x4;
typedef __attribute__((ext_vector_type(4))) unsigned short us4;
typedef __attribute__((ext_vector_type(8))) unsigned short us8;

typedef __attribute__((address_space(3))) void lds_void;
typedef const __attribute__((address_space(1))) void glob_void;

__device__ __forceinline__ void gll16(const void* g, void* l) {
  __builtin_amdgcn_global_load_lds((glob_void*)g, (lds_void*)l, 16, 0, 0);
}

__device__ __forceinline__ unsigned short f2bf(float x) {
  union { float f; unsigned u; } a; a.f = x;
  unsigned r = a.u + 0x7FFFu + ((a.u >> 16) & 1u);
  return (unsigned short)(r >> 16);
}
__device__ __forceinline__ float bf2f(unsigned short b) {
  union { float f; unsigned u; } a; a.u = ((unsigned)b) << 16;
  return a.f;
}

// ---------------- prep: inputs -> A3 = [Ah | Ah | Al] (bf16, [4096][1536]) ----
__global__ __launch_bounds__(256) void prep_inputs(const float* __restrict__ x,
                                                   unsigned short* __restrict__ A3) {
  int idx = blockIdx.x * 256 + threadIdx.x;
  int n = idx >> 9, c = idx & 511;
  float v = x[idx];
  unsigned short hi = f2bf(v);
  unsigned short lo = f2bf(v - bf2f(hi));
  size_t base = (size_t)n * K3;
  A3[base + c] = hi;
  A3[base + 512 + c] = hi;
  A3[base + 1024 + c] = lo;
}

// ---------------- prep: weights -> B3T [512 c][1536 k] = [Wh;Wl;Wh]^T, PhT ----
__global__ __launch_bounds__(256) void prep_weights(const float* __restrict__ w,
                                                    const float* __restrict__ pw,
                                                    unsigned short* __restrict__ B3T,
                                                    unsigned short* __restrict__ PhT) {
  int idx = blockIdx.x * 256 + threadIdx.x;
  int c = idx >> 9, k = idx & 511;
  float v = w[(size_t)k * HD + c];
  unsigned short hi = f2bf(v);
  unsigned short lo = f2bf(v - bf2f(hi));
  size_t base = (size_t)c * K3;
  B3T[base + k] = hi;
  B3T[base + 512 + k] = lo;
  B3T[base + 1024 + k] = hi;
  float p = pw[(size_t)k * HD + c];
  PhT[(size_t)c * IND + k] = f2bf(p);
}

// ---------------- GEMM 128x128, BK=64, XCD-swizzled, fused f1f2 + ST^T -------
// z=0: support-acc = A3 @ B3T^T (K=1536); writes ST bf16^T + g1/g2 (fused f1f2)
// z=1: resid = Ah @ PhT^T (K=512) + projb + bias
__global__ __launch_bounds__(256) void gemm_kernel(
    const unsigned short* __restrict__ A3, const unsigned short* __restrict__ B3T,
    const unsigned short* __restrict__ PhT,
    unsigned short* __restrict__ ST, float* __restrict__ resid,
    float* __restrict__ g1, float* __restrict__ g2,
    const float* __restrict__ wu, const float* __restrict__ wv,
    const float* __restrict__ projb, const float* __restrict__ bias) {
  const int z = blockIdx.z;
  // XCD swizzle: same-m blocks land on same XCD (L%8 preserved = bx%8)
  int L = blockIdx.x + 32 * blockIdx.y;          // 0..127
  int xcd = L & 7, idx = L >> 3;
  const int by = idx & 3;
  const int bx = (idx >> 2) * 8 + xcd;
  const unsigned short* Bp = z ? PhT : B3T;
  const int ldb = z ? IND : K3;
  const int K = z ? IND : K3;
  const int m0 = bx * 128;
  const int n0 = by * 128;
  const int tid = threadIdx.x;
  const int lane = tid & 63;
  const int wvv_ = tid >> 6;
  const int wm = wvv_ & 1, wn = wvv_ >> 1;
  const int lrow = lane & 15;
  const int kg = lane >> 4;

  // one explicit 64KB arena, manually partitioned (no adjacency assumptions):
  //   main loop: As[buf] = sh + buf*8192 ; Bs[buf] = sh + 16384 + buf*8192
  //   epilogue:  lst = sh[0..17408) (34.8KB) ; f12 = (float*)(sh+17920) (2KB)
  __shared__ __align__(16) unsigned short sh[32768];

  f32x4 acc[4][4];
#pragma unroll
  for (int a = 0; a < 4; ++a)
#pragma unroll
    for (int b = 0; b < 4; ++b) acc[a][b] = (f32x4){0.f, 0.f, 0.f, 0.f};

  // slot sl of row rr holds k-chunk sl^(rr&7): linear gll dest + pre-swizzled src
  auto STAGE = [&](int buf, int k0) {
    unsigned short* Asb = sh + buf * 8192;
    unsigned short* Bsb = sh + 16384 + buf * 8192;
#pragma unroll
    for (int s = 0; s < 4; ++s) {
      int c = s * 256 + tid;
      int rr = c >> 3, sl = c & 7;
      int ko = sl ^ (rr & 7);
      gll16(A3 + (size_t)(m0 + rr) * K3 + k0 + ko * 8, Asb + c * 8);
    }
#pragma unroll
    for (int s = 0; s < 4; ++s) {
      int c = s * 256 + tid;
      int rr = c >> 3, sl = c & 7;
      int ko = sl ^ (rr & 7);
      gll16(Bp + (size_t)(n0 + rr) * ldb + k0 + ko * 8, Bsb + c * 8);
    }
  };

  STAGE(0, 0);
  __syncthreads();

  int buf = 0;
  for (int k0 = 0; k0 < K; k0 += 64) {
    if (k0 + 64 < K) STAGE(buf ^ 1, k0 + 64);
    const unsigned short* Asb = sh + buf * 8192;
    const unsigned short* Bsb = sh + 16384 + buf * 8192;
#pragma unroll
    for (int ks = 0; ks < 2; ++ks) {
      int cb = ks * 4 + kg;
      bf16x8 af[4], bfr[4];
#pragma unroll
      for (int mf = 0; mf < 4; ++mf) {
        int row = wm * 64 + mf * 16 + lrow;
        af[mf] = *(const bf16x8*)(Asb + row * 64 + (cb ^ (row & 7)) * 8);
      }
#pragma unroll
      for (int nf = 0; nf < 4; ++nf) {
        int row = wn * 64 + nf * 16 + lrow;
        bfr[nf] = *(const bf16x8*)(Bsb + row * 64 + (cb ^ (row & 7)) * 8);
      }
#pragma unroll
      for (int mf = 0; mf < 4; ++mf)
#pragma unroll
        for (int nf = 0; nf < 4; ++nf)
          acc[mf][nf] = __builtin_amdgcn_mfma_f32_16x16x32_bf16(af[mf], bfr[nf], acc[mf][nf], 0, 0, 0);
    }
    __syncthreads();
    buf ^= 1;
  }

  const int lcol = lane & 15;
  if (z == 0) {
    // ---- fused f1/f2: row-dots with wu/wv from f32 acc ----
    float wuv[4], wvvv[4];
#pragma unroll
    for (int nf = 0; nf < 4; ++nf) {
      int cg = n0 + wn * 64 + nf * 16 + lcol;
      wuv[nf] = wu[cg]; wvvv[nf] = wv[cg];
    }
    float du[4][4], dv[4][4];
#pragma unroll
    for (int mf = 0; mf < 4; ++mf)
#pragma unroll
      for (int q = 0; q < 4; ++q) {
        float a = 0.f, b = 0.f;
#pragma unroll
        for (int nf = 0; nf < 4; ++nf) {
          a += acc[mf][nf][q] * wuv[nf];
          b += acc[mf][nf][q] * wvvv[nf];
        }
#pragma unroll
        for (int m = 1; m < 16; m <<= 1) {
          a += __shfl_xor(a, m);
          b += __shfl_xor(b, m);
        }
        du[mf][q] = a; dv[mf][q] = b;
      }
    float* f12 = (float*)(sh + 17920);           // [2 uv][2 wn][128] = 2KB
    if (lcol == 0) {
#pragma unroll
      for (int mf = 0; mf < 4; ++mf)
#pragma unroll
        for (int q = 0; q < 4; ++q) {
          int rowl = wm * 64 + mf * 16 + kg * 4 + q;
          f12[wn * 128 + rowl] = du[mf][q];
          f12[256 + wn * 128 + rowl] = dv[mf][q];
        }
    }
    // ---- ST transpose via LDS: lst[128 col][136 rows-padded] bf16 ----
    unsigned short* lst = sh;                    // 17408 shorts, disjoint from f12
#pragma unroll
    for (int mf = 0; mf < 4; ++mf)
#pragma unroll
      for (int nf = 0; nf < 4; ++nf) {
        int coll = wn * 64 + nf * 16 + lcol;
        int row4 = wm * 64 + mf * 16 + kg * 4;
        us4 st4;
#pragma unroll
        for (int q = 0; q < 4; ++q) st4[q] = f2bf(acc[mf][nf][q]);
        *(us4*)(&lst[coll * 136 + row4]) = st4;
      }
    __syncthreads();
    // g1/g2 write
    {
      int row = tid & 127, sel = tid >> 7;
      float vs = f12[sel * 256 + row] + f12[sel * 256 + 128 + row];
      float* gp = sel ? g2 : g1;
      gp[by * NN + m0 + row] = vs * 1.4426950408889634f;
    }
    // ST write: coalesced 256B runs per column
#pragma unroll
    for (int k = 0; k < 8; ++k) {
      int col = k * 16 + (tid >> 4);
      int chunk = tid & 15;
      us8 v = *(const us8*)(&lst[col * 136 + chunk * 8]);
      *(us8*)(ST + (size_t)(n0 + col) * NN + m0 + chunk * 8) = v;
    }
  } else {
#pragma unroll
    for (int mf = 0; mf < 4; ++mf)
#pragma unroll
      for (int nf = 0; nf < 4; ++nf) {
        int rg = m0 + wm * 64 + mf * 16 + kg * 4;
        int cg = n0 + wn * 64 + nf * 16 + lcol;
        float addv = projb[cg] + bias[cg];
#pragma unroll
        for (int q = 0; q < 4; ++q)
          resid[(size_t)(rg + q) * HD + cg] = acc[mf][nf][q] + addv;
      }
  }
}

// ---------------- adjacency -> transposed bitmask bmT[word][i] ---------------
__global__ __launch_bounds__(256) void ballot_kernel(const float* __restrict__ adj,
                                                     unsigned long long* __restrict__ bmT) {
  int i = blockIdx.x;
  int tid = threadIdx.x, lane = tid & 63, wvv_ = tid >> 6;
  const float* arow = adj + (size_t)i * NN;
#pragma unroll 4
  for (int it = 0; it < 16; ++it) {
    int j = it * 256 + tid;
    unsigned long long b = __ballot(arow[j] != 0.0f);
    if (lane == 0) bmT[(size_t)(it * 4 + wvv_) * NN + i] = b;
  }
}

// ---------------- fused masked softmax + PV + residual (barrier-free loop) ---
// grid (128 tiles of 32 rows, 4 heads); 4 waves, wave w owns j in [w*1024,+1024)
__global__ __launch_bounds__(256) void attn_kernel(
    const unsigned short* __restrict__ ST,        // [512 d][4096 j] bf16
    const unsigned long long* __restrict__ bmT,   // [64 word][4096 i]
    const float* __restrict__ g1, const float* __restrict__ g2,
    const float* __restrict__ resid, float* __restrict__ out) {
  const int bx = blockIdx.x;
  const int by = blockIdx.y;
  const int tid = threadIdx.x;
  const int lane = tid & 63;
  const int w = tid >> 6;
  const int il = lane & 15;
  const int kg = lane >> 4;
  const int i0 = bx * 32;

  __shared__ unsigned short tile[4][2][4096];     // 64KB: per-wave dbuf [128 d][32 j]

  const float g2v0 = g2[by * NN + i0 + il];
  const float g2v1 = g2[by * NN + i0 + il + 16];
  const float g2v0h = 0.2f * g2v0, g2v1h = 0.2f * g2v1;
  const float* g1h = g1 + by * NN + w * 1024;
  const unsigned short* STh = ST + (size_t)(by * 128) * NN + w * 1024;
  const unsigned char* mb0 = (const unsigned char*)bmT + ((size_t)(i0 + il) << 3) + kg;
  const unsigned char* mb1 = mb0 + 128;

  // per-lane stage source geometry: m = s*64+lane -> dr = s*16+(lane>>2),
  // jq = (lane&3)^((lane>>3)&3)  (s-independent)
  const int dr0 = lane >> 2;
  const int jq = (lane & 3) ^ ((lane >> 3) & 3);
  const unsigned short* src0 = STh + (size_t)dr0 * NN + jq * 8;

  auto STAGE = [&](int buf, int J) {
#pragma unroll
    for (int s = 0; s < 8; ++s)
      gll16(src0 + (size_t)s * 16 * NN + J, &tile[w][buf][s * 512]);
  };
  auto MOFF = [&](int t) -> size_t {
    return ((size_t)(w * 16 + (t >> 1)) * (NN * 8)) + (size_t)((t & 1) * 4);
  };

  // B-fragment LDS offset (shorts): row=d*16+il, slot = kg ^ ((il>>1)&3)
  const int rb = il * 32 + (kg ^ ((il >> 1) & 3)) * 8;

  bf16x8 ones;
#pragma unroll
  for (int e = 0; e < 8; ++e) ones[e] = (short)0x3F80;

  f32x4 acc[2][8];
#pragma unroll
  for (int g = 0; g < 2; ++g)
#pragma unroll
    for (int d = 0; d < 8; ++d) acc[g][d] = (f32x4){0.f, 0.f, 0.f, 0.f};
  f32x4 asum0 = (f32x4){0.f, 0.f, 0.f, 0.f};
  f32x4 asum1 = (f32x4){0.f, 0.f, 0.f, 0.f};

  // prologue: batch(0) = 8 gll16 + 4 reg loads
  STAGE(0, 0);
  f32x4 g1c0 = *(const f32x4*)(g1h + kg * 8);
  f32x4 g1c1 = *(const f32x4*)(g1h + kg * 8 + 4);
  unsigned mbc0 = mb0[MOFF(0)];
  unsigned mbc1 = mb1[MOFF(0)];
  f32x4 g1n0, g1n1;
  unsigned mbn0 = 0, mbn1 = 0;

  int buf = 0;
  for (int t = 0; t < 32; ++t) {
    if (t < 31) {
      STAGE(buf ^ 1, (t + 1) * 32);
      int tn = t + 1;
      g1n0 = *(const f32x4*)(g1h + tn * 32 + kg * 8);
      g1n1 = *(const f32x4*)(g1h + tn * 32 + kg * 8 + 4);
      size_t mo = MOFF(tn);
      mbn0 = mb0[mo];
      mbn1 = mb1[mo];
      // keep only this iteration's issue (8 gll + 4 reg) in flight; retires
      // ALL of stage(t-1) regardless of compiler load reordering
      asm volatile("s_waitcnt vmcnt(12)" ::: "memory");
    } else {
      asm volatile("s_waitcnt vmcnt(0)" ::: "memory");
    }
    const unsigned short* tb = &tile[w][buf][0];
    bf16x8 bc[8];
#pragma unroll
    for (int d = 0; d < 8; ++d)
      bc[d] = *(const bf16x8*)(tb + d * 512 + rb);

    union F8 { f32x4 v[2]; float f[8]; } gc;
    gc.v[0] = g1c0; gc.v[1] = g1c1;
    float p0[8], p1[8];
#pragma unroll
    for (int e = 0; e < 8; ++e) {
      float t0 = gc.f[e] + g2v0;
      float b0 = __builtin_fmaf(0.2f, gc.f[e], g2v0h);
      float pe0 = __builtin_amdgcn_exp2f(fmaxf(t0, b0));
      union { float f; unsigned u; } u0; u0.f = pe0;
      u0.u &= (unsigned)(-(int)((mbc0 >> e) & 1u));
      p0[e] = u0.f;
      float t1 = gc.f[e] + g2v1;
      float b1 = __builtin_fmaf(0.2f, gc.f[e], g2v1h);
      float pe1 = __builtin_amdgcn_exp2f(fmaxf(t1, b1));
      union { float f; unsigned u; } u1; u1.f = pe1;
      u1.u &= (unsigned)(-(int)((mbc1 >> e) & 1u));
      p1[e] = u1.f;
    }
    union { unsigned u[4]; bf16x8 v; } af0, af1;
#pragma unroll
    for (int e2 = 0; e2 < 4; ++e2) {
      unsigned pk;
      asm("v_cvt_pk_bf16_f32 %0, %1, %2" : "=v"(pk) : "v"(p0[2 * e2]), "v"(p0[2 * e2 + 1]));
      af0.u[e2] = pk;
      asm("v_cvt_pk_bf16_f32 %0, %1, %2" : "=v"(pk) : "v"(p1[2 * e2]), "v"(p1[2 * e2 + 1]));
      af1.u[e2] = pk;
    }
#pragma unroll
    for (int d = 0; d < 8; ++d) {
      acc[0][d] = __builtin_amdgcn_mfma_f32_16x16x32_bf16(af0.v, bc[d], acc[0][d], 0, 0, 0);
      acc[1][d] = __builtin_amdgcn_mfma_f32_16x16x32_bf16(af1.v, bc[d], acc[1][d], 0, 0, 0);
    }
    asum0 = __builtin_amdgcn_mfma_f32_16x16x32_bf16(af0.v, ones, asum0, 0, 0, 0);
    asum1 = __builtin_amdgcn_mfma_f32_16x16x32_bf16(af1.v, ones, asum1, 0, 0, 0);

    g1c0 = g1n0; g1c1 = g1n1; mbc0 = mbn0; mbc1 = mbn1;
    buf ^= 1;
  }

  // ---- epilogue: cross-wave reduce in LDS, normalize, +resid, write out ----
  __syncthreads();
  float* fl = (float*)&tile[0][0][0];             // 16384 floats
  if (il == 0) {
#pragma unroll
    for (int q = 0; q < 4; ++q) {
      fl[w * 4096 + kg * 4 + q] = asum0[q];
      fl[w * 4096 + 16 + kg * 4 + q] = asum1[q];
    }
  }
  __syncthreads();
  const int row = tid >> 3, cb = tid & 7;
  float ssum = fl[row] + fl[4096 + row] + fl[8192 + row] + fl[12288 + row];
  float rs = ssum > 0.0f ? 1.0f / ssum : 0.0f;
  __syncthreads();
#pragma unroll
  for (int g = 0; g < 2; ++g)
#pragma unroll
    for (int d = 0; d < 8; ++d)
#pragma unroll
      for (int q = 0; q < 4; ++q)
        fl[w * 4096 + (g * 16 + kg * 4 + q) * 128 + d * 16 + il] =
            (g ? acc[1][d][q] : acc[0][d][q]);
  __syncthreads();
  const float* rres = resid + (size_t)(i0 + row) * HD + by * 128 + cb * 16;
  float* po = out + (size_t)(i0 + row) * HD + by * 128 + cb * 16;
#pragma unroll
  for (int q4 = 0; q4 < 4; ++q4) {
    int o = row * 128 + cb * 16 + q4 * 4;
    f32x4 s0 = *(const f32x4*)(&fl[o]);
    f32x4 s1 = *(const f32x4*)(&fl[4096 + o]);
    f32x4 s2 = *(const f32x4*)(&fl[8192 + o]);
    f32x4 s3 = *(const f32x4*)(&fl[12288 + o]);
    f32x4 rr = *(const f32x4*)(rres + q4 * 4);
    f32x4 ov;
#pragma unroll
    for (int q = 0; q < 4; ++q)
      ov[q] = (s0[q] + s1[q] + s2[q] + s3[q]) * rs + rr[q];
    *(f32x4*)(po + q4 * 4) = ov;
  }
}

// ---------------- launcher ---------------------------------------------------
extern "C" void kernel_launch(void* const* d_in, const int* in_sizes, int n_in,
                              void* d_out, int out_size, void* d_ws, size_t ws_size,
                              hipStream_t stream) {
  const float* inputs = (const float*)d_in[0];
  const float* adj = (const float*)d_in[1];
  const float* weight = (const float*)d_in[2];
  const float* wu = (const float*)d_in[3];
  const float* wv = (const float*)d_in[4];
  const float* bias = (const float*)d_in[5];
  const float* projw = (const float*)d_in[6];
  const float* projb = (const float*)d_in[7];
  float* out = (float*)d_out;

  char* ws = (char*)d_ws;
  size_t off = 0;
  unsigned short* A3 = (unsigned short*)(ws + off); off += (size_t)NN * K3 * 2;          // 12.58MB
  unsigned short* B3T = (unsigned short*)(ws + off); off += (size_t)HD * K3 * 2;         // 1.57MB
  unsigned short* PhT = (unsigned short*)(ws + off); off += (size_t)HD * IND * 2;        // 0.52MB
  unsigned short* ST = (unsigned short*)(ws + off); off += (size_t)HD * NN * 2;          // 4MB
  float* resid = (float*)(ws + off); off += (size_t)NN * HD * 4;                         // 8.39MB
  float* g1 = (float*)(ws + off); off += (size_t)NH * NN * 4;
  float* g2 = (float*)(ws + off); off += (size_t)NH * NN * 4;
  unsigned long long* bmT = (unsigned long long*)(ws + off); off += (size_t)NN * 64 * 8; // 2MB

  prep_inputs<<<(NN * IND) / 256, 256, 0, stream>>>(inputs, A3);
  prep_weights<<<(IND * HD) / 256, 256, 0, stream>>>(weight, projw, B3T, PhT);
  gemm_kernel<<<dim3(32, 4, 2), 256, 0, stream>>>(A3, B3T, PhT, ST, resid, g1, g2,
                                                  wu, wv, projb, bias);
  ballot_kernel<<<NN, 256, 0, stream>>>(adj, bmT);
  attn_kernel<<<dim3(128, 4), 256, 0, stream>>>(ST, bmT, g1, g2, resid, out);
}

// Round 8
// 198.652 us; speedup vs baseline: 1.4460x; 1.0068x over previous
//
#include <hip/hip_runtime.h>

#define NN 4096      // nodes
#define IND 512      // input dim
#define HD 512       // H*D
#define NH 4         // heads
#define DH 128       // per-head dim
#define K3 1536      // split-K for support GEMM

typedef __attribute__((ext_vector_type(8))) short bf16x8;
typedef __attribute__((ext_vector_type(4))) float f32x4;
typedef __attribute__((ext_vector_type(4))) unsigned short us4;
typedef __attribute__((ext_vector_type(8))) unsigned short us8;

typedef __attribute__((address_space(3))) void lds_void;
typedef const __attribute__((address_space(1))) void glob_void;

__device__ __forceinline__ void gll16(const void* g, void* l) {
  __builtin_amdgcn_global_load_lds((glob_void*)g, (lds_void*)l, 16, 0, 0);
}

__device__ __forceinline__ unsigned short f2bf(float x) {
  union { float f; unsigned u; } a; a.f = x;
  unsigned r = a.u + 0x7FFFu + ((a.u >> 16) & 1u);
  return (unsigned short)(r >> 16);
}
__device__ __forceinline__ float bf2f(unsigned short b) {
  union { float f; unsigned u; } a; a.u = ((unsigned)b) << 16;
  return a.f;
}

// ---------------- prep: inputs -> A3 = [Ah | Ah | Al] (bf16, vectorized x4) --
__global__ __launch_bounds__(256) void prep_inputs(const float* __restrict__ x,
                                                   unsigned short* __restrict__ A3) {
  int idx = blockIdx.x * 256 + threadIdx.x;       // f32x4 groups: 0..524287
  int n = idx >> 7, c4 = (idx & 127) * 4;
  f32x4 v = *(const f32x4*)(x + (size_t)n * IND + c4);
  us4 hi, lo;
#pragma unroll
  for (int e = 0; e < 4; ++e) {
    hi[e] = f2bf(v[e]);
    lo[e] = f2bf(v[e] - bf2f(hi[e]));
  }
  size_t base = (size_t)n * K3 + c4;
  *(us4*)(A3 + base) = hi;
  *(us4*)(A3 + base + 512) = hi;
  *(us4*)(A3 + base + 1024) = lo;
}

// ---------------- prep: weights -> B3T [512 c][1536 k] = [Wh;Wl;Wh]^T, PhT ----
__global__ __launch_bounds__(256) void prep_weights(const float* __restrict__ w,
                                                    const float* __restrict__ pw,
                                                    unsigned short* __restrict__ B3T,
                                                    unsigned short* __restrict__ PhT) {
  int idx = blockIdx.x * 256 + threadIdx.x;
  int c = idx >> 9, k = idx & 511;
  float v = w[(size_t)k * HD + c];
  unsigned short hi = f2bf(v);
  unsigned short lo = f2bf(v - bf2f(hi));
  size_t base = (size_t)c * K3;
  B3T[base + k] = hi;
  B3T[base + 512 + k] = lo;
  B3T[base + 1024 + k] = hi;
  float p = pw[(size_t)k * HD + c];
  PhT[(size_t)c * IND + k] = f2bf(p);
}

// ---------------- GEMM 128x128, BK=64, XCD-swizzled, fused f1f2 + ST^T -------
// z=0: support-acc = A3 @ B3T^T (K=1536); writes ST bf16^T + g1/g2 (fused f1f2)
// z=1: resid = Ah @ PhT^T (K=512) + projb + bias
__global__ __launch_bounds__(256) void gemm_kernel(
    const unsigned short* __restrict__ A3, const unsigned short* __restrict__ B3T,
    const unsigned short* __restrict__ PhT,
    unsigned short* __restrict__ ST, float* __restrict__ resid,
    float* __restrict__ g1, float* __restrict__ g2,
    const float* __restrict__ wu, const float* __restrict__ wv,
    const float* __restrict__ projb, const float* __restrict__ bias) {
  const int z = blockIdx.z;
  // XCD swizzle: same-m blocks land on same XCD (L%8 preserved = bx%8)
  int L = blockIdx.x + 32 * blockIdx.y;          // 0..127
  int xcd = L & 7, idx = L >> 3;
  const int by = idx & 3;
  const int bx = (idx >> 2) * 8 + xcd;
  const unsigned short* Bp = z ? PhT : B3T;
  const int ldb = z ? IND : K3;
  const int K = z ? IND : K3;
  const int m0 = bx * 128;
  const int n0 = by * 128;
  const int tid = threadIdx.x;
  const int lane = tid & 63;
  const int wvv_ = tid >> 6;
  const int wm = wvv_ & 1, wn = wvv_ >> 1;
  const int lrow = lane & 15;
  const int kg = lane >> 4;

  // one explicit 64KB arena, manually partitioned (no adjacency assumptions):
  //   main loop: As[buf] = sh + buf*8192 ; Bs[buf] = sh + 16384 + buf*8192
  //   epilogue:  lst = sh[0..17408) (34.8KB) ; f12 = (float*)(sh+17920) (2KB)
  __shared__ __align__(16) unsigned short sh[32768];

  f32x4 acc[4][4];
#pragma unroll
  for (int a = 0; a < 4; ++a)
#pragma unroll
    for (int b = 0; b < 4; ++b) acc[a][b] = (f32x4){0.f, 0.f, 0.f, 0.f};

  // slot sl of row rr holds k-chunk sl^(rr&7): linear gll dest + pre-swizzled src
  auto STAGE = [&](int buf, int k0) {
    unsigned short* Asb = sh + buf * 8192;
    unsigned short* Bsb = sh + 16384 + buf * 8192;
#pragma unroll
    for (int s = 0; s < 4; ++s) {
      int c = s * 256 + tid;
      int rr = c >> 3, sl = c & 7;
      int ko = sl ^ (rr & 7);
      gll16(A3 + (size_t)(m0 + rr) * K3 + k0 + ko * 8, Asb + c * 8);
    }
#pragma unroll
    for (int s = 0; s < 4; ++s) {
      int c = s * 256 + tid;
      int rr = c >> 3, sl = c & 7;
      int ko = sl ^ (rr & 7);
      gll16(Bp + (size_t)(n0 + rr) * ldb + k0 + ko * 8, Bsb + c * 8);
    }
  };

  STAGE(0, 0);
  __syncthreads();

  int buf = 0;
  for (int k0 = 0; k0 < K; k0 += 64) {
    if (k0 + 64 < K) STAGE(buf ^ 1, k0 + 64);
    const unsigned short* Asb = sh + buf * 8192;
    const unsigned short* Bsb = sh + 16384 + buf * 8192;
#pragma unroll
    for (int ks = 0; ks < 2; ++ks) {
      int cb = ks * 4 + kg;
      bf16x8 af[4], bfr[4];
#pragma unroll
      for (int mf = 0; mf < 4; ++mf) {
        int row = wm * 64 + mf * 16 + lrow;
        af[mf] = *(const bf16x8*)(Asb + row * 64 + (cb ^ (row & 7)) * 8);
      }
#pragma unroll
      for (int nf = 0; nf < 4; ++nf) {
        int row = wn * 64 + nf * 16 + lrow;
        bfr[nf] = *(const bf16x8*)(Bsb + row * 64 + (cb ^ (row & 7)) * 8);
      }
#pragma unroll
      for (int mf = 0; mf < 4; ++mf)
#pragma unroll
        for (int nf = 0; nf < 4; ++nf)
          acc[mf][nf] = __builtin_amdgcn_mfma_f32_16x16x32_bf16(af[mf], bfr[nf], acc[mf][nf], 0, 0, 0);
    }
    __syncthreads();
    buf ^= 1;
  }

  const int lcol = lane & 15;
  if (z == 0) {
    // ---- fused f1/f2: row-dots with wu/wv from f32 acc ----
    float wuv[4], wvvv[4];
#pragma unroll
    for (int nf = 0; nf < 4; ++nf) {
      int cg = n0 + wn * 64 + nf * 16 + lcol;
      wuv[nf] = wu[cg]; wvvv[nf] = wv[cg];
    }
    float du[4][4], dv[4][4];
#pragma unroll
    for (int mf = 0; mf < 4; ++mf)
#pragma unroll
      for (int q = 0; q < 4; ++q) {
        float a = 0.f, b = 0.f;
#pragma unroll
        for (int nf = 0; nf < 4; ++nf) {
          a += acc[mf][nf][q] * wuv[nf];
          b += acc[mf][nf][q] * wvvv[nf];
        }
#pragma unroll
        for (int m = 1; m < 16; m <<= 1) {
          a += __shfl_xor(a, m);
          b += __shfl_xor(b, m);
        }
        du[mf][q] = a; dv[mf][q] = b;
      }
    float* f12 = (float*)(sh + 17920);           // [2 uv][2 wn][128] = 2KB
    if (lcol == 0) {
#pragma unroll
      for (int mf = 0; mf < 4; ++mf)
#pragma unroll
        for (int q = 0; q < 4; ++q) {
          int rowl = wm * 64 + mf * 16 + kg * 4 + q;
          f12[wn * 128 + rowl] = du[mf][q];
          f12[256 + wn * 128 + rowl] = dv[mf][q];
        }
    }
    // ---- ST transpose via LDS: lst[128 col][136 rows-padded] bf16 ----
    unsigned short* lst = sh;                    // 17408 shorts, disjoint from f12
#pragma unroll
    for (int mf = 0; mf < 4; ++mf)
#pragma unroll
      for (int nf = 0; nf < 4; ++nf) {
        int coll = wn * 64 + nf * 16 + lcol;
        int row4 = wm * 64 + mf * 16 + kg * 4;
        us4 st4;
#pragma unroll
        for (int q = 0; q < 4; ++q) st4[q] = f2bf(acc[mf][nf][q]);
        *(us4*)(&lst[coll * 136 + row4]) = st4;
      }
    __syncthreads();
    // g1/g2 write
    {
      int row = tid & 127, sel = tid >> 7;
      float vs = f12[sel * 256 + row] + f12[sel * 256 + 128 + row];
      float* gp = sel ? g2 : g1;
      gp[by * NN + m0 + row] = vs * 1.4426950408889634f;
    }
    // ST write: coalesced 256B runs per column
#pragma unroll
    for (int k = 0; k < 8; ++k) {
      int col = k * 16 + (tid >> 4);
      int chunk = tid & 15;
      us8 v = *(const us8*)(&lst[col * 136 + chunk * 8]);
      *(us8*)(ST + (size_t)(n0 + col) * NN + m0 + chunk * 8) = v;
    }
  } else {
#pragma unroll
    for (int mf = 0; mf < 4; ++mf)
#pragma unroll
      for (int nf = 0; nf < 4; ++nf) {
        int rg = m0 + wm * 64 + mf * 16 + kg * 4;
        int cg = n0 + wn * 64 + nf * 16 + lcol;
        float addv = projb[cg] + bias[cg];
#pragma unroll
        for (int q = 0; q < 4; ++q)
          resid[(size_t)(rg + q) * HD + cg] = acc[mf][nf][q] + addv;
      }
  }
}

// ---------------- adjacency -> transposed bitmask bmT[word][i] ---------------
__global__ __launch_bounds__(256) void ballot_kernel(const float* __restrict__ adj,
                                                     unsigned long long* __restrict__ bmT) {
  int i = blockIdx.x;
  int tid = threadIdx.x, lane = tid & 63, wvv_ = tid >> 6;
  const float* arow = adj + (size_t)i * NN;
#pragma unroll 4
  for (int it = 0; it < 16; ++it) {
    int j = it * 256 + tid;
    unsigned long long b = __ballot(arow[j] != 0.0f);
    if (lane == 0) bmT[(size_t)(it * 4 + wvv_) * NN + i] = b;
  }
}

// ---------------- fused masked softmax + PV + residual (barrier-free loop) ---
// grid (128 tiles of 32 rows, 4 heads); 4 waves, wave w owns j in [w*1024,+1024)
// __launch_bounds__(256,2): LDS (64KB) pins occupancy at 2 blocks/CU = 2 waves/
// SIMD regardless of VGPR, so allow up to 256 VGPR -> bc[8]+acc fully live,
// batched ds_reads hide under the softmax-VALU phase (R7: 92 VGPR forced
// per-d read->wait->MFMA serialization).
__global__ __launch_bounds__(256, 2) void attn_kernel(
    const unsigned short* __restrict__ ST,        // [512 d][4096 j] bf16
    const unsigned long long* __restrict__ bmT,   // [64 word][4096 i]
    const float* __restrict__ g1, const float* __restrict__ g2,
    const float* __restrict__ resid, float* __restrict__ out) {
  const int bx = blockIdx.x;
  const int by = blockIdx.y;
  const int tid = threadIdx.x;
  const int lane = tid & 63;
  const int w = tid >> 6;
  const int il = lane & 15;
  const int kg = lane >> 4;
  const int i0 = bx * 32;

  __shared__ unsigned short tile[4][2][4096];     // 64KB: per-wave dbuf [128 d][32 j]

  const float g2v0 = g2[by * NN + i0 + il];
  const float g2v1 = g2[by * NN + i0 + il + 16];
  const float g2v0h = 0.2f * g2v0, g2v1h = 0.2f * g2v1;
  const float* g1h = g1 + by * NN + w * 1024;
  const unsigned short* STh = ST + (size_t)(by * 128) * NN + w * 1024;
  const unsigned char* mb0 = (const unsigned char*)bmT + ((size_t)(i0 + il) << 3) + kg;
  const unsigned char* mb1 = mb0 + 128;

  // per-lane stage source geometry: m = s*64+lane -> dr = s*16+(lane>>2),
  // jq = (lane&3)^((lane>>3)&3)  (s-independent)
  const int dr0 = lane >> 2;
  const int jq = (lane & 3) ^ ((lane >> 3) & 3);
  const unsigned short* src0 = STh + (size_t)dr0 * NN + jq * 8;

  auto STAGE = [&](int buf, int J) {
#pragma unroll
    for (int s = 0; s < 8; ++s)
      gll16(src0 + (size_t)s * 16 * NN + J, &tile[w][buf][s * 512]);
  };
  auto MOFF = [&](int t) -> size_t {
    return ((size_t)(w * 16 + (t >> 1)) * (NN * 8)) + (size_t)((t & 1) * 4);
  };

  // B-fragment LDS offset (shorts): row=d*16+il, slot = kg ^ ((il>>1)&3)
  const int rb = il * 32 + (kg ^ ((il >> 1) & 3)) * 8;

  bf16x8 ones;
#pragma unroll
  for (int e = 0; e < 8; ++e) ones[e] = (short)0x3F80;

  f32x4 acc[2][8];
#pragma unroll
  for (int g = 0; g < 2; ++g)
#pragma unroll
    for (int d = 0; d < 8; ++d) acc[g][d] = (f32x4){0.f, 0.f, 0.f, 0.f};
  f32x4 asum0 = (f32x4){0.f, 0.f, 0.f, 0.f};
  f32x4 asum1 = (f32x4){0.f, 0.f, 0.f, 0.f};

  // prologue: batch(0) = 8 gll16 + 4 reg loads
  STAGE(0, 0);
  f32x4 g1c0 = *(const f32x4*)(g1h + kg * 8);
  f32x4 g1c1 = *(const f32x4*)(g1h + kg * 8 + 4);
  unsigned mbc0 = mb0[MOFF(0)];
  unsigned mbc1 = mb1[MOFF(0)];
  f32x4 g1n0, g1n1;
  unsigned mbn0 = 0, mbn1 = 0;

  int buf = 0;
  for (int t = 0; t < 32; ++t) {
    if (t < 31) {
      STAGE(buf ^ 1, (t + 1) * 32);
      int tn = t + 1;
      g1n0 = *(const f32x4*)(g1h + tn * 32 + kg * 8);
      g1n1 = *(const f32x4*)(g1h + tn * 32 + kg * 8 + 4);
      size_t mo = MOFF(tn);
      mbn0 = mb0[mo];
      mbn1 = mb1[mo];
      // keep only this iteration's issue (8 gll + 4 reg) in flight; retires
      // ALL of stage(t-1) regardless of compiler load reordering
      asm volatile("s_waitcnt vmcnt(12)" ::: "memory");
    } else {
      asm volatile("s_waitcnt vmcnt(0)" ::: "memory");
    }
    const unsigned short* tb = &tile[w][buf][0];
    bf16x8 bc[8];
#pragma unroll
    for (int d = 0; d < 8; ++d)
      bc[d] = *(const bf16x8*)(tb + d * 512 + rb);

    union F8 { f32x4 v[2]; float f[8]; } gc;
    gc.v[0] = g1c0; gc.v[1] = g1c1;
    float p0[8], p1[8];
#pragma unroll
    for (int e = 0; e < 8; ++e) {
      float t0 = gc.f[e] + g2v0;
      float b0 = __builtin_fmaf(0.2f, gc.f[e], g2v0h);
      float pe0 = __builtin_amdgcn_exp2f(fmaxf(t0, b0));
      union { float f; unsigned u; } u0; u0.f = pe0;
      u0.u &= (unsigned)(-(int)((mbc0 >> e) & 1u));
      p0[e] = u0.f;
      float t1 = gc.f[e] + g2v1;
      float b1 = __builtin_fmaf(0.2f, gc.f[e], g2v1h);
      float pe1 = __builtin_amdgcn_exp2f(fmaxf(t1, b1));
      union { float f; unsigned u; } u1; u1.f = pe1;
      u1.u &= (unsigned)(-(int)((mbc1 >> e) & 1u));
      p1[e] = u1.f;
    }
    union { unsigned u[4]; bf16x8 v; } af0, af1;
#pragma unroll
    for (int e2 = 0; e2 < 4; ++e2) {
      unsigned pk;
      asm("v_cvt_pk_bf16_f32 %0, %1, %2" : "=v"(pk) : "v"(p0[2 * e2]), "v"(p0[2 * e2 + 1]));
      af0.u[e2] = pk;
      asm("v_cvt_pk_bf16_f32 %0, %1, %2" : "=v"(pk) : "v"(p1[2 * e2]), "v"(p1[2 * e2 + 1]));
      af1.u[e2] = pk;
    }
    __builtin_amdgcn_s_setprio(1);
#pragma unroll
    for (int d = 0; d < 8; ++d) {
      acc[0][d] = __builtin_amdgcn_mfma_f32_16x16x32_bf16(af0.v, bc[d], acc[0][d], 0, 0, 0);
      acc[1][d] = __builtin_amdgcn_mfma_f32_16x16x32_bf16(af1.v, bc[d], acc[1][d], 0, 0, 0);
    }
    asum0 = __builtin_amdgcn_mfma_f32_16x16x32_bf16(af0.v, ones, asum0, 0, 0, 0);
    asum1 = __builtin_amdgcn_mfma_f32_16x16x32_bf16(af1.v, ones, asum1, 0, 0, 0);
    __builtin_amdgcn_s_setprio(0);

    g1c0 = g1n0; g1c1 = g1n1; mbc0 = mbn0; mbc1 = mbn1;
    buf ^= 1;
  }

  // ---- epilogue: cross-wave reduce in LDS, normalize, +resid, write out ----
  __syncthreads();
  float* fl = (float*)&tile[0][0][0];             // 16384 floats
  if (il == 0) {
#pragma unroll
    for (int q = 0; q < 4; ++q) {
      fl[w * 4096 + kg * 4 + q] = asum0[q];
      fl[w * 4096 + 16 + kg * 4 + q] = asum1[q];
    }
  }
  __syncthreads();
  const int row = tid >> 3, cb = tid & 7;
  float ssum = fl[row] + fl[4096 + row] + fl[8192 + row] + fl[12288 + row];
  float rs = ssum > 0.0f ? 1.0f / ssum : 0.0f;
  __syncthreads();
#pragma unroll
  for (int g = 0; g < 2; ++g)
#pragma unroll
    for (int d = 0; d < 8; ++d)
#pragma unroll
      for (int q = 0; q < 4; ++q)
        fl[w * 4096 + (g * 16 + kg * 4 + q) * 128 + d * 16 + il] =
            (g ? acc[1][d][q] : acc[0][d][q]);
  __syncthreads();
  const float* rres = resid + (size_t)(i0 + row) * HD + by * 128 + cb * 16;
  float* po = out + (size_t)(i0 + row) * HD + by * 128 + cb * 16;
#pragma unroll
  for (int q4 = 0; q4 < 4; ++q4) {
    int o = row * 128 + cb * 16 + q4 * 4;
    f32x4 s0 = *(const f32x4*)(&fl[o]);
    f32x4 s1 = *(const f32x4*)(&fl[4096 + o]);
    f32x4 s2 = *(const f32x4*)(&fl[8192 + o]);
    f32x4 s3 = *(const f32x4*)(&fl[12288 + o]);
    f32x4 rr = *(const f32x4*)(rres + q4 * 4);
    f32x4 ov;
#pragma unroll
    for (int q = 0; q < 4; ++q)
      ov[q] = (s0[q] + s1[q] + s2[q] + s3[q]) * rs + rr[q];
    *(f32x4*)(po + q4 * 4) = ov;
  }
}

// ---------------- launcher ---------------------------------------------------
extern "C" void kernel_launch(void* const* d_in, const int* in_sizes, int n_in,
                              void* d_out, int out_size, void* d_ws, size_t ws_size,
                              hipStream_t stream) {
  const float* inputs = (const float*)d_in[0];
  const float* adj = (const float*)d_in[1];
  const float* weight = (const float*)d_in[2];
  const float* wu = (const float*)d_in[3];
  const float* wv = (const float*)d_in[4];
  const float* bias = (const float*)d_in[5];
  const float* projw = (const float*)d_in[6];
  const float* projb = (const float*)d_in[7];
  float* out = (float*)d_out;

  char* ws = (char*)d_ws;
  size_t off = 0;
  unsigned short* A3 = (unsigned short*)(ws + off); off += (size_t)NN * K3 * 2;          // 12.58MB
  unsigned short* B3T = (unsigned short*)(ws + off); off += (size_t)HD * K3 * 2;         // 1.57MB
  unsigned short* PhT = (unsigned short*)(ws + off); off += (size_t)HD * IND * 2;        // 0.52MB
  unsigned short* ST = (unsigned short*)(ws + off); off += (size_t)HD * NN * 2;          // 4MB
  float* resid = (float*)(ws + off); off += (size_t)NN * HD * 4;                         // 8.39MB
  float* g1 = (float*)(ws + off); off += (size_t)NH * NN * 4;
  float* g2 = (float*)(ws + off); off += (size_t)NH * NN * 4;
  unsigned long long* bmT = (unsigned long long*)(ws + off); off += (size_t)NN * 64 * 8; // 2MB

  prep_inputs<<<(NN * IND) / 1024, 256, 0, stream>>>(inputs, A3);
  prep_weights<<<(IND * HD) / 256, 256, 0, stream>>>(weight, projw, B3T, PhT);
  gemm_kernel<<<dim3(32, 4, 2), 256, 0, stream>>>(A3, B3T, PhT, ST, resid, g1, g2,
                                                  wu, wv, projb, bias);
  ballot_kernel<<<NN, 256, 0, stream>>>(adj, bmT);
  attn_kernel<<<dim3(128, 4), 256, 0, stream>>>(ST, bmT, g1, g2, resid, out);
}

// Round 9
// 197.059 us; speedup vs baseline: 1.4577x; 1.0081x over previous
//
#include <hip/hip_runtime.h>

#define NN 4096      // nodes
#define IND 512      // input dim
#define HD 512       // H*D
#define NH 4         // heads
#define DH 128       // per-head dim
#define K3 1536      // split-K for support GEMM

typedef __attribute__((ext_vector_type(8))) short bf16x8;
typedef __attribute__((ext_vector_type(4))) float f32x4;
typedef __attribute__((ext_vector_type(4))) unsigned short us4;
typedef __attribute__((ext_vector_type(8))) unsigned short us8;

typedef __attribute__((address_space(3))) void lds_void;
typedef const __attribute__((address_space(1))) void glob_void;

__device__ __forceinline__ void gll16(const void* g, void* l) {
  __builtin_amdgcn_global_load_lds((glob_void*)g, (lds_void*)l, 16, 0, 0);
}

__device__ __forceinline__ unsigned short f2bf(float x) {
  union { float f; unsigned u; } a; a.f = x;
  unsigned r = a.u + 0x7FFFu + ((a.u >> 16) & 1u);
  return (unsigned short)(r >> 16);
}
__device__ __forceinline__ float bf2f(unsigned short b) {
  union { float f; unsigned u; } a; a.u = ((unsigned)b) << 16;
  return a.f;
}

// ---------------- fused prep: inputs->A3 (x4 vec) + weights->B3T/PhT ---------
__global__ __launch_bounds__(256) void prep_kernel(
    const float* __restrict__ x, const float* __restrict__ w,
    const float* __restrict__ pw,
    unsigned short* __restrict__ A3, unsigned short* __restrict__ B3T,
    unsigned short* __restrict__ PhT) {
  int bid = blockIdx.x;
  if (bid < 2048) {
    int idx = bid * 256 + threadIdx.x;            // f32x4 groups: 0..524287
    int n = idx >> 7, c4 = (idx & 127) * 4;
    f32x4 v = *(const f32x4*)(x + (size_t)n * IND + c4);
    us4 hi, lo;
#pragma unroll
    for (int e = 0; e < 4; ++e) {
      hi[e] = f2bf(v[e]);
      lo[e] = f2bf(v[e] - bf2f(hi[e]));
    }
    size_t base = (size_t)n * K3 + c4;
    *(us4*)(A3 + base) = hi;
    *(us4*)(A3 + base + 512) = hi;
    *(us4*)(A3 + base + 1024) = lo;
  } else {
    int idx = (bid - 2048) * 256 + threadIdx.x;   // 0..262143
    int c = idx >> 9, k = idx & 511;
    float v = w[(size_t)k * HD + c];
    unsigned short hi = f2bf(v);
    unsigned short lo = f2bf(v - bf2f(hi));
    size_t base = (size_t)c * K3;
    B3T[base + k] = hi;
    B3T[base + 512 + k] = lo;
    B3T[base + 1024 + k] = hi;
    float p = pw[(size_t)k * HD + c];
    PhT[(size_t)c * IND + k] = f2bf(p);
  }
}

// ---------------- GEMM 128x128, BK=64, XCD-swizzled, fused f1f2 + ST^T -------
// z=0: support-acc = A3 @ B3T^T (K=1536); writes ST bf16^T + g1/g2 (fused f1f2)
// z=1: resid = Ah @ PhT^T (K=512) + projb + bias
__global__ __launch_bounds__(256) void gemm_kernel(
    const unsigned short* __restrict__ A3, const unsigned short* __restrict__ B3T,
    const unsigned short* __restrict__ PhT,
    unsigned short* __restrict__ ST, float* __restrict__ resid,
    float* __restrict__ g1, float* __restrict__ g2,
    const float* __restrict__ wu, const float* __restrict__ wv,
    const float* __restrict__ projb, const float* __restrict__ bias) {
  const int z = blockIdx.z;
  // XCD swizzle: same-m blocks land on same XCD (L%8 preserved = bx%8)
  int L = blockIdx.x + 32 * blockIdx.y;          // 0..127
  int xcd = L & 7, idx = L >> 3;
  const int by = idx & 3;
  const int bx = (idx >> 2) * 8 + xcd;
  const unsigned short* Bp = z ? PhT : B3T;
  const int ldb = z ? IND : K3;
  const int K = z ? IND : K3;
  const int m0 = bx * 128;
  const int n0 = by * 128;
  const int tid = threadIdx.x;
  const int lane = tid & 63;
  const int wvv_ = tid >> 6;
  const int wm = wvv_ & 1, wn = wvv_ >> 1;
  const int lrow = lane & 15;
  const int kg = lane >> 4;

  // one explicit 64KB arena, manually partitioned:
  //   main loop: As[buf] = sh + buf*8192 ; Bs[buf] = sh + 16384 + buf*8192
  //   epilogue:  lst = sh[0..17408) (34.8KB) ; f12 = (float*)(sh+17920) (2KB)
  __shared__ __align__(16) unsigned short sh[32768];

  f32x4 acc[4][4];
#pragma unroll
  for (int a = 0; a < 4; ++a)
#pragma unroll
    for (int b = 0; b < 4; ++b) acc[a][b] = (f32x4){0.f, 0.f, 0.f, 0.f};

  // slot sl of row rr holds k-chunk sl^(rr&7): linear gll dest + pre-swizzled src
  auto STAGE = [&](int buf, int k0) {
    unsigned short* Asb = sh + buf * 8192;
    unsigned short* Bsb = sh + 16384 + buf * 8192;
#pragma unroll
    for (int s = 0; s < 4; ++s) {
      int c = s * 256 + tid;
      int rr = c >> 3, sl = c & 7;
      int ko = sl ^ (rr & 7);
      gll16(A3 + (size_t)(m0 + rr) * K3 + k0 + ko * 8, Asb + c * 8);
    }
#pragma unroll
    for (int s = 0; s < 4; ++s) {
      int c = s * 256 + tid;
      int rr = c >> 3, sl = c & 7;
      int ko = sl ^ (rr & 7);
      gll16(Bp + (size_t)(n0 + rr) * ldb + k0 + ko * 8, Bsb + c * 8);
    }
  };

  STAGE(0, 0);
  __syncthreads();

  int buf = 0;
  for (int k0 = 0; k0 < K; k0 += 64) {
    if (k0 + 64 < K) STAGE(buf ^ 1, k0 + 64);
    const unsigned short* Asb = sh + buf * 8192;
    const unsigned short* Bsb = sh + 16384 + buf * 8192;
#pragma unroll
    for (int ks = 0; ks < 2; ++ks) {
      int cb = ks * 4 + kg;
      bf16x8 af[4], bfr[4];
#pragma unroll
      for (int mf = 0; mf < 4; ++mf) {
        int row = wm * 64 + mf * 16 + lrow;
        af[mf] = *(const bf16x8*)(Asb + row * 64 + (cb ^ (row & 7)) * 8);
      }
#pragma unroll
      for (int nf = 0; nf < 4; ++nf) {
        int row = wn * 64 + nf * 16 + lrow;
        bfr[nf] = *(const bf16x8*)(Bsb + row * 64 + (cb ^ (row & 7)) * 8);
      }
#pragma unroll
      for (int mf = 0; mf < 4; ++mf)
#pragma unroll
        for (int nf = 0; nf < 4; ++nf)
          acc[mf][nf] = __builtin_amdgcn_mfma_f32_16x16x32_bf16(af[mf], bfr[nf], acc[mf][nf], 0, 0, 0);
    }
    __syncthreads();
    buf ^= 1;
  }

  const int lcol = lane & 15;
  if (z == 0) {
    // ---- fused f1/f2: row-dots with wu/wv from f32 acc ----
    float wuv[4], wvvv[4];
#pragma unroll
    for (int nf = 0; nf < 4; ++nf) {
      int cg = n0 + wn * 64 + nf * 16 + lcol;
      wuv[nf] = wu[cg]; wvvv[nf] = wv[cg];
    }
    float du[4][4], dv[4][4];
#pragma unroll
    for (int mf = 0; mf < 4; ++mf)
#pragma unroll
      for (int q = 0; q < 4; ++q) {
        float a = 0.f, b = 0.f;
#pragma unroll
        for (int nf = 0; nf < 4; ++nf) {
          a += acc[mf][nf][q] * wuv[nf];
          b += acc[mf][nf][q] * wvvv[nf];
        }
#pragma unroll
        for (int m = 1; m < 16; m <<= 1) {
          a += __shfl_xor(a, m);
          b += __shfl_xor(b, m);
        }
        du[mf][q] = a; dv[mf][q] = b;
      }
    float* f12 = (float*)(sh + 17920);           // [2 uv][2 wn][128] = 2KB
    if (lcol == 0) {
#pragma unroll
      for (int mf = 0; mf < 4; ++mf)
#pragma unroll
        for (int q = 0; q < 4; ++q) {
          int rowl = wm * 64 + mf * 16 + kg * 4 + q;
          f12[wn * 128 + rowl] = du[mf][q];
          f12[256 + wn * 128 + rowl] = dv[mf][q];
        }
    }
    // ---- ST transpose via LDS: lst[128 col][136 rows-padded] bf16 ----
    unsigned short* lst = sh;                    // 17408 shorts, disjoint from f12
#pragma unroll
    for (int mf = 0; mf < 4; ++mf)
#pragma unroll
      for (int nf = 0; nf < 4; ++nf) {
        int coll = wn * 64 + nf * 16 + lcol;
        int row4 = wm * 64 + mf * 16 + kg * 4;
        us4 st4;
#pragma unroll
        for (int q = 0; q < 4; ++q) st4[q] = f2bf(acc[mf][nf][q]);
        *(us4*)(&lst[coll * 136 + row4]) = st4;
      }
    __syncthreads();
    // g1/g2 write
    {
      int row = tid & 127, sel = tid >> 7;
      float vs = f12[sel * 256 + row] + f12[sel * 256 + 128 + row];
      float* gp = sel ? g2 : g1;
      gp[by * NN + m0 + row] = vs * 1.4426950408889634f;
    }
    // ST write: coalesced 256B runs per column
#pragma unroll
    for (int k = 0; k < 8; ++k) {
      int col = k * 16 + (tid >> 4);
      int chunk = tid & 15;
      us8 v = *(const us8*)(&lst[col * 136 + chunk * 8]);
      *(us8*)(ST + (size_t)(n0 + col) * NN + m0 + chunk * 8) = v;
    }
  } else {
#pragma unroll
    for (int mf = 0; mf < 4; ++mf)
#pragma unroll
      for (int nf = 0; nf < 4; ++nf) {
        int rg = m0 + wm * 64 + mf * 16 + kg * 4;
        int cg = n0 + wn * 64 + nf * 16 + lcol;
        float addv = projb[cg] + bias[cg];
#pragma unroll
        for (int q = 0; q < 4; ++q)
          resid[(size_t)(rg + q) * HD + cg] = acc[mf][nf][q] + addv;
      }
  }
}

// ---------------- adjacency -> transposed bitmask bmT[word][i] ---------------
__global__ __launch_bounds__(256) void ballot_kernel(const float* __restrict__ adj,
                                                     unsigned long long* __restrict__ bmT) {
  int i = blockIdx.x;
  int tid = threadIdx.x, lane = tid & 63, wvv_ = tid >> 6;
  const float* arow = adj + (size_t)i * NN;
#pragma unroll 4
  for (int it = 0; it < 16; ++it) {
    int j = it * 256 + tid;
    unsigned long long b = __ballot(arow[j] != 0.0f);
    if (lane == 0) bmT[(size_t)(it * 4 + wvv_) * NN + i] = b;
  }
}

// ---------------- fused masked softmax + PV partials (64 rows/block) ---------
// grid (64 tiles of 64 rows, 4 heads, 2 j-halves); 4 waves, wave w owns
// j in [w*512,+512) of its half. 64 rows/block halves ST re-read traffic
// (R8 theory: L3-BW-bound at ~10.7 TB/s on 512MB of ST re-reads).
__global__ __launch_bounds__(256, 2) void attn_kernel(
    const unsigned short* __restrict__ ST,        // [512 d][4096 j] bf16
    const unsigned long long* __restrict__ bmT,   // [64 word][4096 i]
    const float* __restrict__ g1, const float* __restrict__ g2,
    float* __restrict__ P0, float* __restrict__ P1, float* __restrict__ S) {
  const int bx = blockIdx.x;
  const int by = blockIdx.y;
  const int bz = blockIdx.z;
  const int tid = threadIdx.x;
  const int lane = tid & 63;
  const int w = tid >> 6;
  const int il = lane & 15;
  const int kg = lane >> 4;
  const int i0 = bx * 64;

  __shared__ unsigned short tile[4][2][4096];     // 64KB: per-wave dbuf [128 d][32 j]

  float g2v[4];
#pragma unroll
  for (int g = 0; g < 4; ++g) g2v[g] = g2[by * NN + i0 + g * 16 + il];

  const float* g1h = g1 + by * NN + bz * 2048 + w * 512;
  const unsigned short* STh = ST + (size_t)(by * 128) * NN + bz * 2048 + w * 512;
  const unsigned char* mbp0 = (const unsigned char*)bmT + ((size_t)(i0 + il) << 3) + kg;
  // row-group g adds g*16 rows * 8B = g*128 bytes
  auto MOFF = [&](int t) -> size_t {
    return ((size_t)(bz * 32 + w * 8 + (t >> 1)) * (NN * 8)) + (size_t)((t & 1) * 4);
  };

  // per-lane stage source geometry: row dr0+s*16, chunk jq (swizzled)
  const int dr0 = lane >> 2;
  const int jq = (lane & 3) ^ ((lane >> 3) & 3);
  const unsigned short* src0 = STh + (size_t)dr0 * NN + jq * 8;
  auto STAGE = [&](int buf, int J) {
#pragma unroll
    for (int s = 0; s < 8; ++s)
      gll16(src0 + (size_t)s * 16 * NN + J, &tile[w][buf][s * 512]);
  };

  // B-fragment LDS offset (shorts): row=d*16+il, slot = kg ^ ((il>>1)&3)
  const int rb = il * 32 + (kg ^ ((il >> 1) & 3)) * 8;

  bf16x8 ones;
#pragma unroll
  for (int e = 0; e < 8; ++e) ones[e] = (short)0x3F80;

  f32x4 acc[4][8];
#pragma unroll
  for (int g = 0; g < 4; ++g)
#pragma unroll
    for (int d = 0; d < 8; ++d) acc[g][d] = (f32x4){0.f, 0.f, 0.f, 0.f};
  f32x4 asum[4];
#pragma unroll
  for (int g = 0; g < 4; ++g) asum[g] = (f32x4){0.f, 0.f, 0.f, 0.f};

  // prologue: 8 gll + 2 g1 loads + 4 mask bytes = 14 VMEM per iter
  STAGE(0, 0);
  f32x4 g1c0 = *(const f32x4*)(g1h + kg * 8);
  f32x4 g1c1 = *(const f32x4*)(g1h + kg * 8 + 4);
  unsigned mbc[4], mbn[4] = {0, 0, 0, 0};
  {
    size_t mo = MOFF(0);
#pragma unroll
    for (int g = 0; g < 4; ++g) mbc[g] = mbp0[mo + g * 128];
  }
  f32x4 g1n0, g1n1;

  int buf = 0;
  for (int t = 0; t < 16; ++t) {
    if (t < 15) {
      STAGE(buf ^ 1, (t + 1) * 32);
      g1n0 = *(const f32x4*)(g1h + (t + 1) * 32 + kg * 8);
      g1n1 = *(const f32x4*)(g1h + (t + 1) * 32 + kg * 8 + 4);
      size_t mo = MOFF(t + 1);
#pragma unroll
      for (int g = 0; g < 4; ++g) mbn[g] = mbp0[mo + g * 128];
      // retires all of stage(t) (issued last iter); keeps this iter's 14 in flight
      asm volatile("s_waitcnt vmcnt(14)" ::: "memory");
    } else {
      asm volatile("s_waitcnt vmcnt(0)" ::: "memory");
    }
    const unsigned short* tb = &tile[w][buf][0];
    bf16x8 bc[8];
#pragma unroll
    for (int d = 0; d < 8; ++d)
      bc[d] = *(const bf16x8*)(tb + d * 512 + rb);

    union F8 { f32x4 v[2]; float f[8]; } gc;
    gc.v[0] = g1c0; gc.v[1] = g1c1;
#pragma unroll
    for (int g = 0; g < 4; ++g) {
      float p[8];
#pragma unroll
      for (int e = 0; e < 8; ++e) {
        float a = gc.f[e] + g2v[g];                 // t*log2e
        float m = fmaxf(a, 0.2f * a);               // leaky-relu (log2e-scaled)
        float pe = __builtin_amdgcn_exp2f(m);       // no max-sub (shift-invariant)
        union { float f; unsigned u; } pu; pu.f = pe;
        pu.u &= (unsigned)(-(int)((mbc[g] >> e) & 1u));
        p[e] = pu.f;
      }
      union { unsigned u[4]; bf16x8 v; } af;
#pragma unroll
      for (int e2 = 0; e2 < 4; ++e2) {
        unsigned pk;
        asm("v_cvt_pk_bf16_f32 %0, %1, %2" : "=v"(pk) : "v"(p[2 * e2]), "v"(p[2 * e2 + 1]));
        af.u[e2] = pk;
      }
      __builtin_amdgcn_s_setprio(1);
#pragma unroll
      for (int d = 0; d < 8; ++d)
        acc[g][d] = __builtin_amdgcn_mfma_f32_16x16x32_bf16(af.v, bc[d], acc[g][d], 0, 0, 0);
      asum[g] = __builtin_amdgcn_mfma_f32_16x16x32_bf16(af.v, ones, asum[g], 0, 0, 0);
      __builtin_amdgcn_s_setprio(0);
    }
    g1c0 = g1n0; g1c1 = g1n1;
#pragma unroll
    for (int g = 0; g < 4; ++g) mbc[g] = mbn[g];
    buf ^= 1;
  }

  // ---- epilogue: S cross-wave sum, then acc reduce in 2 passes of 32 rows ----
  __syncthreads();
  float* fl = (float*)&tile[0][0][0];             // 16384 floats
  if (il == 0) {
#pragma unroll
    for (int g = 0; g < 4; ++g)
#pragma unroll
      for (int q = 0; q < 4; ++q)
        fl[w * 64 + g * 16 + kg * 4 + q] = asum[g][q];
  }
  __syncthreads();
  if (tid < 64) {
    float s = fl[tid] + fl[64 + tid] + fl[128 + tid] + fl[192 + tid];
    S[((size_t)bz * 4 + by) * NN + i0 + tid] = s;
  }
  __syncthreads();
  float* P = bz ? P1 : P0;
#pragma unroll
  for (int pass = 0; pass < 2; ++pass) {
#pragma unroll
    for (int gg = 0; gg < 2; ++gg) {
      int g = pass * 2 + gg;
#pragma unroll
      for (int d = 0; d < 8; ++d)
#pragma unroll
        for (int q = 0; q < 4; ++q)
          fl[w * 4096 + (gg * 16 + kg * 4 + q) * 128 + d * 16 + il] =
              acc[g][d][q];
    }
    __syncthreads();
    {
      int r = tid >> 3, cb = tid & 7;
      float* prow = P + (size_t)(i0 + pass * 32 + r) * HD + by * 128 + cb * 16;
#pragma unroll
      for (int q4 = 0; q4 < 4; ++q4) {
        int o = r * 128 + cb * 16 + q4 * 4;
        f32x4 s0 = *(const f32x4*)(&fl[o]);
        f32x4 s1 = *(const f32x4*)(&fl[4096 + o]);
        f32x4 s2 = *(const f32x4*)(&fl[8192 + o]);
        f32x4 s3 = *(const f32x4*)(&fl[12288 + o]);
        f32x4 ov;
#pragma unroll
        for (int q = 0; q < 4; ++q) ov[q] = s0[q] + s1[q] + s2[q] + s3[q];
        *(f32x4*)(prow + q4 * 4) = ov;
      }
    }
    __syncthreads();
  }
}

// ---------------- merge partials + normalize + residual ----------------------
__global__ __launch_bounds__(256) void merge_kernel(const float* __restrict__ P0,
                                                    const float* __restrict__ P1,
                                                    const float* __restrict__ S,
                                                    const float* __restrict__ resid,
                                                    float* __restrict__ out) {
  int idx = blockIdx.x * 256 + threadIdx.x;   // 0..524287 (f32x4 groups)
  int i = idx >> 7;
  int c = (idx & 127) * 4;
  int h = c >> 7;
  f32x4 v0 = *(const f32x4*)(P0 + (size_t)i * HD + c);
  f32x4 v1 = *(const f32x4*)(P1 + (size_t)i * HD + c);
  float s = S[(size_t)h * NN + i] + S[(size_t)(4 + h) * NN + i];
  float rs = s > 0.0f ? 1.0f / s : 0.0f;
  f32x4 rr = *(const f32x4*)(resid + (size_t)i * HD + c);
  f32x4 o;
#pragma unroll
  for (int q = 0; q < 4; ++q) o[q] = (v0[q] + v1[q]) * rs + rr[q];
  *(f32x4*)(out + (size_t)i * HD + c) = o;
}

// ---------------- launcher ---------------------------------------------------
extern "C" void kernel_launch(void* const* d_in, const int* in_sizes, int n_in,
                              void* d_out, int out_size, void* d_ws, size_t ws_size,
                              hipStream_t stream) {
  const float* inputs = (const float*)d_in[0];
  const float* adj = (const float*)d_in[1];
  const float* weight = (const float*)d_in[2];
  const float* wu = (const float*)d_in[3];
  const float* wv = (const float*)d_in[4];
  const float* bias = (const float*)d_in[5];
  const float* projw = (const float*)d_in[6];
  const float* projb = (const float*)d_in[7];
  float* out = (float*)d_out;

  char* ws = (char*)d_ws;
  size_t off = 0;
  unsigned short* A3 = (unsigned short*)(ws + off); off += (size_t)NN * K3 * 2;          // 12.58MB
  unsigned short* B3T = (unsigned short*)(ws + off); off += (size_t)HD * K3 * 2;         // ->14.16MB
  unsigned short* PhT = (unsigned short*)(ws + off); off += (size_t)HD * IND * 2;        // ->14.68MB
  unsigned short* ST = (unsigned short*)(ws + off); off += (size_t)HD * NN * 2;          // ->18.87MB
  float* resid = (float*)(ws + off); off += (size_t)NN * HD * 4;                         // ->27.26MB
  float* g1 = (float*)(ws + off); off += (size_t)NH * NN * 4;
  float* g2 = (float*)(ws + off); off += (size_t)NH * NN * 4;                            // ->27.39MB
  unsigned long long* bmT = (unsigned long long*)(ws + off); off += (size_t)NN * 64 * 8; // ->29.49MB

  // Overlays: A3/B3T/PhT (0..14.68MB) are dead once gemm completes.
  // P0 (8.39MB) + S (128KB) fit in the dead zone; P1 appended after bmT.
  // Peak = 29.49 + 8.39 = 37.88MB < 37.95MB proven in R2.
  float* P0 = (float*)(ws + 0);
  float* S = (float*)(ws + (size_t)NN * HD * 4);                    // 8,388,608
  float* P1 = (float*)(ws + off); off += (size_t)NN * HD * 4;

  prep_kernel<<<3072, 256, 0, stream>>>(inputs, weight, projw, A3, B3T, PhT);
  gemm_kernel<<<dim3(32, 4, 2), 256, 0, stream>>>(A3, B3T, PhT, ST, resid, g1, g2,
                                                  wu, wv, projb, bias);
  ballot_kernel<<<NN, 256, 0, stream>>>(adj, bmT);
  attn_kernel<<<dim3(64, 4, 2), 256, 0, stream>>>(ST, bmT, g1, g2, P0, P1, S);
  merge_kernel<<<2048, 256, 0, stream>>>(P0, P1, S, resid, out);
}